// Round 1
// baseline (1494.088 us; speedup 1.0000x reference)
//
#include <hip/hip_runtime.h>

#define N_NODES 200000
#define N_EDGES 300000
#define N_Q     128
#define N_ENT   50000
#define D       256
#define DSM     64
#define SDIM    128
#define SSM     32

__device__ __forceinline__ float leaky(float x){ return x > 0.f ? x : 0.01f*x; }

// monotone float<->uint mapping for atomicMax on floats
__device__ __forceinline__ unsigned ford(float f){
  unsigned u = __float_as_uint(f);
  return (u & 0x80000000u) ? ~u : (u | 0x80000000u);
}
__device__ __forceinline__ float funord(unsigned u){
  unsigned b = (u & 0x80000000u) ? (u & 0x7FFFFFFFu) : ~u;
  return __uint_as_float(b);
}

// ---------------- init ----------------
__global__ void k_init(float* out, unsigned* segmax, float* denom, float* nns){
  int id = blockIdx.x*256 + threadIdx.x;
  if (id < N_ENT) out[id] = 0.f;
  if (id < N_NODES){ segmax[id] = 0u; denom[id] = 0.f; nns[id] = 0.f; }
}

// ---------------- weight folding ----------------
// Wnl = Wp @ Wl[0:64], Wnr = Wp @ Wr[0:64], Wrl = Wp @ Wl[64:128], Wrr = Wp @ Wr[64:128]
__global__ void k_fold(const float* __restrict__ Wp, const float* __restrict__ Wl,
                       const float* __restrict__ Wr,
                       float* Wnl, float* Wnr, float* Wrl, float* Wrr){
  int id = blockIdx.x*256 + threadIdx.x;          // 4 * 256*64 = 65536
  int m = id >> 14, rem = id & 16383, k = rem >> 6, c = rem & 63;
  const float* Wsrc = (m & 1) ? Wr : Wl;
  int roff = (m >> 1) * 64;
  float s = 0.f;
  for (int i = 0; i < 64; ++i) s += Wp[k*64+i] * Wsrc[(roff+i)*64 + c];
  float* o = (m==0)?Wnl:(m==1)?Wnr:(m==2)?Wrl:Wrr;
  o[k*64+c] = s;
}

// cv[0:64]=b_proj@Wl0, cv[64:128]=b_proj@Wr0, cv[128:192]=b_proj@Wl1, cv[192:256]=b_proj@Wr1
__global__ void k_foldb(const float* __restrict__ bp, const float* __restrict__ Wl,
                        const float* __restrict__ Wr, float* cv){
  int t = threadIdx.x;                             // 256
  int m = t >> 6, c = t & 63;
  const float* Wsrc = (m & 1) ? Wr : Wl;
  int roff = (m >> 1) * 64;
  float s = 0.f;
  for (int i = 0; i < 64; ++i) s += bp[i] * Wsrc[(roff+i)*64 + c];
  cv[t] = s;
}

// qs = q_src@W_static + b_static ; qr = q_rel@W_proj + b_proj
__global__ void k_qproj(const float* __restrict__ qsrc, const float* __restrict__ Ws,
                        const float* __restrict__ bs, const float* __restrict__ qrel,
                        const float* __restrict__ Wp, const float* __restrict__ bp,
                        float* qs, float* qr){
  int id = blockIdx.x*256 + threadIdx.x;           // 128*32 + 128*64 = 12288
  if (id < N_Q*SSM){
    int b = id >> 5, i = id & 31;
    float s = bs[i];
    for (int j = 0; j < SDIM; ++j) s += qsrc[b*SDIM+j] * Ws[j*SSM+i];
    qs[id] = s;
  } else {
    int id2 = id - N_Q*SSM;
    int b = id2 >> 6, i = id2 & 63;
    float s = bp[i];
    for (int j = 0; j < D; ++j) s += qrel[b*D+j] * Wp[j*DSM+i];
    qr[id2] = s;
  }
}

// qctx_{l,r}[b][c] = bias[c] + qs[b]@W[128:160] + qr[b]@W[160:224]
__global__ void k_qctx(const float* __restrict__ qs, const float* __restrict__ qr,
                       const float* __restrict__ Wl, const float* __restrict__ bl,
                       const float* __restrict__ Wr, const float* __restrict__ br,
                       float* qctx_l, float* qctx_r){
  int id = blockIdx.x*256 + threadIdx.x;           // 2 * 128*64 = 16384
  int side = id >> 13, rem = id & 8191, b = rem >> 6, c = rem & 63;
  const float* W = side ? Wr : Wl;
  const float* bias = side ? br : bl;
  float s = bias[c];
  for (int i = 0; i < SSM; ++i) s += qs[b*SSM+i] * W[(128+i)*64+c];
  for (int i = 0; i < DSM; ++i) s += qr[b*DSM+i] * W[(160+i)*64+c];
  (side ? qctx_r : qctx_l)[rem] = s;
}

// ---------------- node pipeline ----------------
// emb2 = leaky(A@Wbs + bbs) (kept in LDS); node_l = emb2@Wnl + cnl; node_r = emb2@Wnr + cnr
__global__ __launch_bounds__(256) void k_node(const float* __restrict__ A,
    const float* __restrict__ Wbs, const float* __restrict__ bbs,
    const float* __restrict__ Wnl, const float* __restrict__ Wnr,
    const float* __restrict__ cv,
    float* __restrict__ node_l, float* __restrict__ node_r){
  __shared__ float sA[32][256];
  __shared__ float sE[32][256];
  int tid = threadIdx.x;
  int row0 = blockIdx.x * 32;                      // 6250*32 == 200000 exactly
  const float4* Ag = (const float4*)(A + (size_t)row0*256);
  float4* sAv = (float4*)&sA[0][0];
  #pragma unroll
  for (int i = 0; i < 8; ++i) sAv[tid + 256*i] = Ag[tid + 256*i];
  __syncthreads();
  int w = tid >> 6, l = tid & 63;
  float acc[8][4];
  #pragma unroll
  for (int r = 0; r < 8; ++r)
    #pragma unroll
    for (int cb = 0; cb < 4; ++cb) acc[r][cb] = 0.f;
  for (int k = 0; k < 256; ++k){
    float w0 = Wbs[k*256 + l];
    float w1 = Wbs[k*256 + l + 64];
    float w2 = Wbs[k*256 + l + 128];
    float w3 = Wbs[k*256 + l + 192];
    #pragma unroll
    for (int r = 0; r < 8; ++r){
      float a = sA[w*8+r][k];
      acc[r][0] += a*w0; acc[r][1] += a*w1; acc[r][2] += a*w2; acc[r][3] += a*w3;
    }
  }
  #pragma unroll
  for (int r = 0; r < 8; ++r)
    #pragma unroll
    for (int cb = 0; cb < 4; ++cb){
      int c = l + 64*cb;
      sE[w*8+r][c] = leaky(acc[r][cb] + bbs[c]);
    }
  __syncthreads();
  float accl[8], accr[8];
  #pragma unroll
  for (int r = 0; r < 8; ++r){ accl[r] = 0.f; accr[r] = 0.f; }
  for (int k = 0; k < 256; ++k){
    float wl = Wnl[k*64 + l];
    float wr = Wnr[k*64 + l];
    #pragma unroll
    for (int r = 0; r < 8; ++r){
      float e = sE[w*8+r][k];
      accl[r] += e*wl; accr[r] += e*wr;
    }
  }
  float cl = cv[l], cr = cv[64+l];
  #pragma unroll
  for (int r = 0; r < 8; ++r){
    int gr = row0 + w*8 + r;
    node_l[(size_t)gr*64 + l] = accl[r] + cl;
    node_r[(size_t)gr*64 + l] = accr[r] + cr;
  }
}

// ---------------- rel pipeline ----------------
// rel_l = rel_emb@Wrl + crl ; rel_r = rel_emb@Wrr + crr   (chunk [e0,e1))
__global__ __launch_bounds__(256) void k_rel(const float* __restrict__ Rm,
    const float* __restrict__ Wrl, const float* __restrict__ Wrr,
    const float* __restrict__ cv,
    float* __restrict__ rel_l, float* __restrict__ rel_r, int e0, int e1){
  __shared__ float sA[64][256];
  int tid = threadIdx.x;
  int row0 = e0 + blockIdx.x * 64;
  #pragma unroll
  for (int i = 0; i < 16; ++i){
    int f = tid + 256*i;                           // float4 index into tile
    int r = f >> 6, c4 = f & 63;
    int gr = row0 + r;
    float4 v = make_float4(0.f,0.f,0.f,0.f);
    if (gr < e1) v = ((const float4*)Rm)[(size_t)gr*64 + c4];
    ((float4*)&sA[0][0])[f] = v;
  }
  __syncthreads();
  int w = tid >> 6, l = tid & 63;
  float accl[16], accr[16];
  #pragma unroll
  for (int r = 0; r < 16; ++r){ accl[r] = 0.f; accr[r] = 0.f; }
  for (int k = 0; k < 256; ++k){
    float wl = Wrl[k*64 + l];
    float wr = Wrr[k*64 + l];
    #pragma unroll
    for (int r = 0; r < 16; ++r){
      float a = sA[w*16+r][k];
      accl[r] += a*wl; accr[r] += a*wr;
    }
  }
  float cl = cv[128+l], cr = cv[192+l];
  #pragma unroll
  for (int r = 0; r < 16; ++r){
    int gr = row0 + w*16 + r;
    if (gr < e1){
      rel_l[(size_t)(gr-e0)*64 + l] = accl[r] + cl;
      rel_r[(size_t)(gr-e0)*64 + l] = accr[r] + cr;
    }
  }
}

// ---------------- edge scoring (one wave per edge) ----------------
__global__ __launch_bounds__(256) void k_edge(const float* __restrict__ node_l,
    const float* __restrict__ node_r, const float* __restrict__ rel_l,
    const float* __restrict__ rel_r, const float* __restrict__ qctx_l,
    const float* __restrict__ qctx_r, const int* __restrict__ src,
    const int* __restrict__ dst, const int* __restrict__ eg,
    const float* __restrict__ Wc, const float* __restrict__ bc,
    float* __restrict__ logits, unsigned* __restrict__ segmax, int e0, int e1){
  __shared__ float sWc[4096];
  int tid = threadIdx.x;
  for (int i = tid; i < 4096; i += 256) sWc[i] = Wc[i];
  __syncthreads();
  int ew = blockIdx.x*4 + (tid >> 6);
  int e = e0 + ew;
  if (e >= e1) return;
  int l = tid & 63;
  int s = src[e], d = dst[e], b = eg[e];
  float lh = leaky(node_l[(size_t)s*64 + l] + rel_l[(size_t)ew*64 + l] + qctx_l[b*64 + l]);
  float rr = leaky(node_r[(size_t)d*64 + l] + rel_r[(size_t)ew*64 + l] + qctx_r[b*64 + l]);
  float rh = bc[l];
  #pragma unroll 8
  for (int i = 0; i < 64; ++i){
    float ri = __shfl(rr, i);
    rh += ri * sWc[i*64 + l];
  }
  float p = lh * rh;
  #pragma unroll
  for (int off = 32; off; off >>= 1) p += __shfl_xor(p, off);
  if (l == 0){
    logits[e] = p;
    atomicMax(&segmax[s], ford(p));
  }
}

// ---------------- softmax + aggregation passes ----------------
__global__ void k_passB(const float* __restrict__ logits_in, float* __restrict__ ex_out,
                        const unsigned* __restrict__ segmax, const int* __restrict__ src,
                        float* __restrict__ denom){
  int e = blockIdx.x*256 + threadIdx.x;
  if (e >= N_EDGES) return;
  int s = src[e];
  float ex = __expf(logits_in[e] - funord(segmax[s]));
  ex_out[e] = ex;
  atomicAdd(&denom[s], ex);
}

__global__ void k_passC(const float* __restrict__ ex, const float* __restrict__ denom,
                        const int* __restrict__ src, const int* __restrict__ dst,
                        const float* __restrict__ node_score, float* __restrict__ nns){
  int e = blockIdx.x*256 + threadIdx.x;
  if (e >= N_EDGES) return;
  int s = src[e];
  float tr = ex[e] / denom[s];
  atomicAdd(&nns[dst[e]], tr * node_score[s]);
}

__global__ void k_passD(const float* __restrict__ nns, const int* __restrict__ ent,
                        float* __restrict__ out){
  int v = blockIdx.x*256 + threadIdx.x;
  if (v >= N_NODES) return;
  atomicAdd(&out[ent[v]], nns[v]);
}

// ---------------- host ----------------
extern "C" void kernel_launch(void* const* d_in, const int* in_sizes, int n_in,
                              void* d_out, int out_size, void* d_ws, size_t ws_size,
                              hipStream_t stream){
  const float* mem   = (const float*)d_in[0];
  const float* nsc   = (const float*)d_in[1];
  const float* relE  = (const float*)d_in[2];
  const float* qsrc  = (const float*)d_in[3];
  const float* qrel  = (const float*)d_in[4];
  const int*   eg    = (const int*)d_in[5];
  const int*   src   = (const int*)d_in[6];
  const int*   dst   = (const int*)d_in[7];
  const int*   ent   = (const int*)d_in[8];
  const float* Wp    = (const float*)d_in[9];
  const float* bp    = (const float*)d_in[10];
  const float* Ws    = (const float*)d_in[11];
  const float* bs    = (const float*)d_in[12];
  const float* Wbs   = (const float*)d_in[13];
  const float* bbs   = (const float*)d_in[14];
  const float* Wl    = (const float*)d_in[15];
  const float* bl    = (const float*)d_in[16];
  const float* Wr    = (const float*)d_in[17];
  const float* br    = (const float*)d_in[18];
  const float* Wc    = (const float*)d_in[19];
  const float* bc    = (const float*)d_in[20];
  float* out = (float*)d_out;

  char* w = (char*)d_ws;
  auto alloc = [&](size_t floats)->float*{
    float* p = (float*)w; w += ((floats*4 + 255)/256)*256; return p;
  };
  float* Wnl = alloc(16384);
  float* Wnr = alloc(16384);
  float* Wrl = alloc(16384);
  float* Wrr = alloc(16384);
  float* cv  = alloc(256);
  float* qs  = alloc((size_t)N_Q*SSM);
  float* qr  = alloc((size_t)N_Q*DSM);
  float* qctx_l = alloc((size_t)N_Q*DSM);
  float* qctx_r = alloc((size_t)N_Q*DSM);
  float* node_l = alloc((size_t)N_NODES*64);
  float* node_r = alloc((size_t)N_NODES*64);
  float* logits = alloc(N_EDGES);
  float* exbuf  = alloc(N_EDGES);
  unsigned* segmax = (unsigned*)alloc(N_NODES);
  float* denom = alloc(N_NODES);
  float* nns   = alloc(N_NODES);
  size_t used = (size_t)(w - (char*)d_ws);
  size_t avail = ws_size > used ? ws_size - used : 0;
  long long chunk = (long long)(avail / 512) & ~63LL;   // 2*64 floats per edge
  if (chunk > N_EDGES) chunk = N_EDGES;
  if (chunk < 64) chunk = 64;
  float* rel_l = alloc((size_t)chunk*64);
  float* rel_r = alloc((size_t)chunk*64);

  k_init<<<(N_NODES+255)/256, 256, 0, stream>>>(out, segmax, denom, nns);
  k_fold<<<256, 256, 0, stream>>>(Wp, Wl, Wr, Wnl, Wnr, Wrl, Wrr);
  k_foldb<<<1, 256, 0, stream>>>(bp, Wl, Wr, cv);
  k_qproj<<<48, 256, 0, stream>>>(qsrc, Ws, bs, qrel, Wp, bp, qs, qr);
  k_qctx<<<64, 256, 0, stream>>>(qs, qr, Wl, bl, Wr, br, qctx_l, qctx_r);
  k_node<<<N_NODES/32, 256, 0, stream>>>(mem, Wbs, bbs, Wnl, Wnr, cv, node_l, node_r);

  for (long long e0 = 0; e0 < N_EDGES; e0 += chunk){
    long long e1 = e0 + chunk; if (e1 > N_EDGES) e1 = N_EDGES;
    int nrows = (int)(e1 - e0);
    k_rel<<<(nrows+63)/64, 256, 0, stream>>>(relE, Wrl, Wrr, cv, rel_l, rel_r, (int)e0, (int)e1);
    k_edge<<<(nrows+3)/4, 256, 0, stream>>>(node_l, node_r, rel_l, rel_r, qctx_l, qctx_r,
                                            src, dst, eg, Wc, bc, logits, segmax, (int)e0, (int)e1);
  }
  k_passB<<<(N_EDGES+255)/256, 256, 0, stream>>>(logits, exbuf, segmax, src, denom);
  k_passC<<<(N_EDGES+255)/256, 256, 0, stream>>>(exbuf, denom, src, dst, nsc, nns);
  k_passD<<<(N_NODES+255)/256, 256, 0, stream>>>(nns, ent, out);
}

// Round 2
// 367.360 us; speedup vs baseline: 4.0671x; 4.0671x over previous
//
#include <hip/hip_runtime.h>

#define N_NODES 200000
#define N_EDGES 300000
#define N_Q     128
#define N_ENT   50000
#define D       256
#define DSM     64
#define SDIM    128
#define SSM     32

typedef __attribute__((ext_vector_type(8))) short bf16x8;
typedef __attribute__((ext_vector_type(4))) float f32x4;

__device__ __forceinline__ float leaky(float x){ return x > 0.f ? x : 0.01f*x; }

__device__ __forceinline__ unsigned ford(float f){
  unsigned u = __float_as_uint(f);
  return (u & 0x80000000u) ? ~u : (u | 0x80000000u);
}
__device__ __forceinline__ float funord(unsigned u){
  unsigned b = (u & 0x80000000u) ? (u & 0x7FFFFFFFu) : ~u;
  return __uint_as_float(b);
}
// fp32 -> bf16 round-to-nearest-even
__device__ __forceinline__ unsigned short f2bf(float f){
  unsigned u = __float_as_uint(f);
  u += 0x7FFFu + ((u >> 16) & 1u);
  return (unsigned short)(u >> 16);
}
__device__ __forceinline__ float bf2f(unsigned short h){
  return __uint_as_float(((unsigned)h) << 16);
}

// ---------------- init ----------------
__global__ void k_init(float* out, unsigned* segmax, float* denom, float* nns){
  int id = blockIdx.x*256 + threadIdx.x;
  if (id < N_ENT) out[id] = 0.f;
  if (id < N_NODES){ segmax[id] = 0u; denom[id] = 0.f; nns[id] = 0.f; }
}

// ---------------- weight folding ----------------
// Wnlr[k][0:64]=Wp@Wl[0:64], Wnlr[k][64:128]=Wp@Wr[0:64]
// Wrlr[k][0:64]=Wp@Wl[64:128], Wrlr[k][64:128]=Wp@Wr[64:128]
__global__ void k_fold(const float* __restrict__ Wp, const float* __restrict__ Wl,
                       const float* __restrict__ Wr, float* Wnlr, float* Wrlr){
  int id = blockIdx.x*256 + threadIdx.x;          // 65536
  int m = id >> 14, rem = id & 16383, k = rem >> 6, c = rem & 63;
  const float* Wsrc = (m & 1) ? Wr : Wl;
  int roff = (m >> 1) * 64;
  float s = 0.f;
  for (int i = 0; i < 64; ++i) s += Wp[k*64+i] * Wsrc[(roff+i)*64 + c];
  float* o = (m >> 1) ? Wrlr : Wnlr;
  o[k*128 + (m&1)*64 + c] = s;
}

// cv[0:64]=bp@Wl0 (node_l bias), cv[64:128]=bp@Wr0, cv[128:192]=bp@Wl1 (rel_l), cv[192:256]=bp@Wr1
__global__ void k_foldb(const float* __restrict__ bp, const float* __restrict__ Wl,
                        const float* __restrict__ Wr, float* cv){
  int t = threadIdx.x;
  int m = t >> 6, c = t & 63;
  const float* Wsrc = (m & 1) ? Wr : Wl;
  int roff = (m >> 1) * 64;
  float s = 0.f;
  for (int i = 0; i < 64; ++i) s += bp[i] * Wsrc[(roff+i)*64 + c];
  cv[t] = s;
}

// pack fp32 [K][N] row-major -> bf16 MFMA B-fragment order.
// frag fb = nb*(K/32)+kb holds 64 lanes x 8 bf16: lane holds
// B[kb*32 + (lane>>4)*8 + i][nb*16 + (lane&15)]
__global__ void k_pack(const float* __restrict__ src, unsigned short* __restrict__ dst,
                       int K, int N, int total){
  int id = blockIdx.x*256 + threadIdx.x;
  if (id >= total) return;
  int lane = id & 63, fb = id >> 6;
  int KB = K >> 5;
  int kb = fb % KB, nb = fb / KB;
  int k0 = kb*32 + ((lane>>4)<<3);
  int n  = nb*16 + (lane & 15);
  #pragma unroll
  for (int i = 0; i < 8; ++i) dst[(size_t)id*8 + i] = f2bf(src[(size_t)(k0+i)*N + n]);
}

// qs = q_src@W_static + b_static ; qr = q_rel@W_proj + b_proj
__global__ void k_qproj(const float* __restrict__ qsrc, const float* __restrict__ Ws,
                        const float* __restrict__ bs, const float* __restrict__ qrel,
                        const float* __restrict__ Wp, const float* __restrict__ bp,
                        float* qs, float* qr){
  int id = blockIdx.x*256 + threadIdx.x;           // 12288
  if (id < N_Q*SSM){
    int b = id >> 5, i = id & 31;
    float s = bs[i];
    for (int j = 0; j < SDIM; ++j) s += qsrc[b*SDIM+j] * Ws[j*SSM+i];
    qs[id] = s;
  } else {
    int id2 = id - N_Q*SSM;
    int b = id2 >> 6, i = id2 & 63;
    float s = bp[i];
    for (int j = 0; j < D; ++j) s += qrel[b*D+j] * Wp[j*DSM+i];
    qr[id2] = s;
  }
}

__global__ void k_qctx(const float* __restrict__ qs, const float* __restrict__ qr,
                       const float* __restrict__ Wl, const float* __restrict__ bl,
                       const float* __restrict__ Wr, const float* __restrict__ br,
                       float* qctx_l, float* qctx_r){
  int id = blockIdx.x*256 + threadIdx.x;           // 16384
  int side = id >> 13, rem = id & 8191, b = rem >> 6, c = rem & 63;
  const float* W = side ? Wr : Wl;
  const float* bias = side ? br : bl;
  float s = bias[c];
  for (int i = 0; i < SSM; ++i) s += qs[b*SSM+i] * W[(128+i)*64+c];
  for (int i = 0; i < DSM; ++i) s += qr[b*DSM+i] * W[(160+i)*64+c];
  (side ? qctx_r : qctx_l)[rem] = s;
}

// ---------------- node pipeline (MFMA) ----------------
// 64 rows/block. sA [64][256] bf16 swizzled; emb2 reuses same LDS.
// phase1: emb2 = leaky(A@Wbs + bbs); phase2: node_lr = emb2@Wnlr + cv
__global__ __launch_bounds__(256) void k_node(const float* __restrict__ A,
    const unsigned short* __restrict__ Wbs_pk, const float* __restrict__ bbs,
    const unsigned short* __restrict__ Wn_pk, const float* __restrict__ cv,
    unsigned short* __restrict__ node_l, unsigned short* __restrict__ node_r){
  __shared__ char smem[32768];
  int tid = threadIdx.x;
  int row0 = blockIdx.x * 64;                      // 3125*64 == 200000
  {
    const float4* Ag = (const float4*)(A + (size_t)row0 * 256);
    #pragma unroll
    for (int it = 0; it < 16; ++it){
      int f = tid + 256*it;
      int r = f >> 6, c4 = f & 63;
      float4 v = Ag[f];
      uint2 u;
      u.x = (unsigned)f2bf(v.x) | ((unsigned)f2bf(v.y) << 16);
      u.y = (unsigned)f2bf(v.z) | ((unsigned)f2bf(v.w) << 16);
      int byte = (r << 9) + (c4 << 3);
      byte ^= (r & 7) << 4;
      *(uint2*)(smem + byte) = u;
    }
  }
  __syncthreads();
  int l = tid & 63, wn = tid >> 6;
  // phase 1: N=256, wave wn covers cols [wn*64, wn*64+64)
  f32x4 acc[4][4];
  #pragma unroll
  for (int mf = 0; mf < 4; ++mf)
    #pragma unroll
    for (int nf = 0; nf < 4; ++nf) acc[mf][nf] = (f32x4){0.f,0.f,0.f,0.f};
  for (int kb = 0; kb < 8; ++kb){
    bf16x8 a[4], b[4];
    #pragma unroll
    for (int mf = 0; mf < 4; ++mf){
      int row = mf*16 + (l & 15);
      int byte = (row << 9) + kb*64 + ((l >> 4) << 4);
      byte ^= (row & 7) << 4;
      a[mf] = *(const bf16x8*)(smem + byte);
    }
    #pragma unroll
    for (int nf = 0; nf < 4; ++nf){
      int nb = wn*4 + nf;
      b[nf] = *(const bf16x8*)(Wbs_pk + ((size_t)(nb*8 + kb)*64 + l)*8);
    }
    #pragma unroll
    for (int mf = 0; mf < 4; ++mf)
      #pragma unroll
      for (int nf = 0; nf < 4; ++nf)
        acc[mf][nf] = __builtin_amdgcn_mfma_f32_16x16x32_bf16(a[mf], b[nf], acc[mf][nf], 0, 0, 0);
  }
  __syncthreads();
  // epilogue 1: bias + leaky -> bf16 emb2 into same LDS (swizzled)
  #pragma unroll
  for (int mf = 0; mf < 4; ++mf)
    #pragma unroll
    for (int nf = 0; nf < 4; ++nf){
      int col = wn*64 + nf*16 + (l & 15);
      float bb = bbs[col];
      #pragma unroll
      for (int r = 0; r < 4; ++r){
        int row = mf*16 + ((l >> 4) << 2) + r;
        int byte = (row << 9) + col*2;
        byte ^= (row & 7) << 4;
        *(unsigned short*)(smem + byte) = f2bf(leaky(acc[mf][nf][r] + bb));
      }
    }
  __syncthreads();
  // phase 2: N=128, wave wn covers cols [wn*32, wn*32+32)
  f32x4 acc2[4][2];
  #pragma unroll
  for (int mf = 0; mf < 4; ++mf){ acc2[mf][0] = (f32x4){0.f,0.f,0.f,0.f}; acc2[mf][1] = (f32x4){0.f,0.f,0.f,0.f}; }
  for (int kb = 0; kb < 8; ++kb){
    bf16x8 a[4], b[2];
    #pragma unroll
    for (int mf = 0; mf < 4; ++mf){
      int row = mf*16 + (l & 15);
      int byte = (row << 9) + kb*64 + ((l >> 4) << 4);
      byte ^= (row & 7) << 4;
      a[mf] = *(const bf16x8*)(smem + byte);
    }
    #pragma unroll
    for (int nf = 0; nf < 2; ++nf){
      int nb = wn*2 + nf;
      b[nf] = *(const bf16x8*)(Wn_pk + ((size_t)(nb*8 + kb)*64 + l)*8);
    }
    #pragma unroll
    for (int mf = 0; mf < 4; ++mf)
      #pragma unroll
      for (int nf = 0; nf < 2; ++nf)
        acc2[mf][nf] = __builtin_amdgcn_mfma_f32_16x16x32_bf16(a[mf], b[nf], acc2[mf][nf], 0, 0, 0);
  }
  #pragma unroll
  for (int mf = 0; mf < 4; ++mf)
    #pragma unroll
    for (int nf = 0; nf < 2; ++nf){
      int col = wn*32 + nf*16 + (l & 15);
      float cc = cv[col];
      #pragma unroll
      for (int r = 0; r < 4; ++r){
        int row = mf*16 + ((l >> 4) << 2) + r;
        unsigned short h = f2bf(acc2[mf][nf][r] + cc);
        size_t g = (size_t)(row0 + row);
        if (col < 64) node_l[g*64 + col] = h;
        else          node_r[g*64 + col - 64] = h;
      }
    }
}

// ---------------- fused rel + edge scoring (MFMA) ----------------
// 64 edges/block. Stage rel_emb tile, GEMM1 -> rel_lr in LDS, gather/compose,
// GEMM2 rh = R@Wc, dot with lh, segment-max.
__global__ __launch_bounds__(256) void k_edge(const float* __restrict__ relE,
    const unsigned short* __restrict__ Wr_pk, const unsigned short* __restrict__ Wc_pk,
    const float* __restrict__ cv, const float* __restrict__ bc,
    const unsigned short* __restrict__ node_l, const unsigned short* __restrict__ node_r,
    const float* __restrict__ qctx_l, const float* __restrict__ qctx_r,
    const int* __restrict__ src, const int* __restrict__ dst, const int* __restrict__ eg,
    float* __restrict__ logits, unsigned* __restrict__ segmax){
  __shared__ char smem[33024];
  unsigned short* sRL  = (unsigned short*)smem;             // [64][128] (aliases staging)
  unsigned short* sL   = (unsigned short*)(smem + 16384);   // [64][64]
  char*           sRin = smem + 24576;                      // [64][64] swizzled
  float*          slog = (float*)(smem + 32768);            // [64]
  int tid = threadIdx.x;
  int e0 = blockIdx.x * 64;
  // stage rel_emb [64][256] bf16 swizzled (full 32KB region)
  {
    const float4* Rg = (const float4*)relE;
    #pragma unroll
    for (int it = 0; it < 16; ++it){
      int f = tid + 256*it;
      int r = f >> 6, c4 = f & 63;
      int ge = e0 + r;
      float4 v = make_float4(0.f,0.f,0.f,0.f);
      if (ge < N_EDGES) v = Rg[(size_t)ge*64 + c4];
      uint2 u;
      u.x = (unsigned)f2bf(v.x) | ((unsigned)f2bf(v.y) << 16);
      u.y = (unsigned)f2bf(v.z) | ((unsigned)f2bf(v.w) << 16);
      int byte = (r << 9) + (c4 << 3);
      byte ^= (r & 7) << 4;
      *(uint2*)(smem + byte) = u;
    }
  }
  __syncthreads();
  int l = tid & 63, wn = tid >> 6;
  // GEMM1: rel_lr[64][128] = tile @ Wrlr ; wave wn covers cols [wn*32, +32)
  f32x4 acc[4][2];
  #pragma unroll
  for (int mf = 0; mf < 4; ++mf){ acc[mf][0] = (f32x4){0.f,0.f,0.f,0.f}; acc[mf][1] = (f32x4){0.f,0.f,0.f,0.f}; }
  for (int kb = 0; kb < 8; ++kb){
    bf16x8 a[4], b[2];
    #pragma unroll
    for (int mf = 0; mf < 4; ++mf){
      int row = mf*16 + (l & 15);
      int byte = (row << 9) + kb*64 + ((l >> 4) << 4);
      byte ^= (row & 7) << 4;
      a[mf] = *(const bf16x8*)(smem + byte);
    }
    #pragma unroll
    for (int nf = 0; nf < 2; ++nf){
      int nb = wn*2 + nf;
      b[nf] = *(const bf16x8*)(Wr_pk + ((size_t)(nb*8 + kb)*64 + l)*8);
    }
    #pragma unroll
    for (int mf = 0; mf < 4; ++mf)
      #pragma unroll
      for (int nf = 0; nf < 2; ++nf)
        acc[mf][nf] = __builtin_amdgcn_mfma_f32_16x16x32_bf16(a[mf], b[nf], acc[mf][nf], 0, 0, 0);
  }
  __syncthreads();
  // epilogue 1: + cv(rel) -> sRL bf16 [64][128] row-major
  #pragma unroll
  for (int mf = 0; mf < 4; ++mf)
    #pragma unroll
    for (int nf = 0; nf < 2; ++nf){
      int col = wn*32 + nf*16 + (l & 15);
      float cc = cv[128 + col];
      #pragma unroll
      for (int r = 0; r < 4; ++r){
        int row = mf*16 + ((l >> 4) << 2) + r;
        sRL[row*128 + col] = f2bf(acc[mf][nf][r] + cc);
      }
    }
  __syncthreads();
  // compose: wave wn handles edges [wn*16, wn*16+16)
  if (tid < 64) slog[tid] = 0.f;
  for (int j = 0; j < 16; ++j){
    int er = wn*16 + j;
    int e = e0 + er;
    int byte = (er << 7) + (l << 1);
    byte ^= (er & 7) << 4;
    if (e < N_EDGES){
      int s = src[e], d2 = dst[e], b = eg[e];
      float lh = leaky(bf2f(node_l[(size_t)s*64 + l]) + bf2f(sRL[er*128 + l])      + qctx_l[b*64 + l]);
      float rr = leaky(bf2f(node_r[(size_t)d2*64 + l]) + bf2f(sRL[er*128 + 64 + l]) + qctx_r[b*64 + l]);
      sL[er*64 + l] = f2bf(lh);
      *(unsigned short*)(sRin + byte) = f2bf(rr);
    } else {
      sL[er*64 + l] = 0;
      *(unsigned short*)(sRin + byte) = 0;
    }
  }
  __syncthreads();
  // GEMM2: RH[64][64] = sRin @ Wc ; wave wn covers cols [wn*16, +16)
  f32x4 acc2[4];
  #pragma unroll
  for (int mf = 0; mf < 4; ++mf) acc2[mf] = (f32x4){0.f,0.f,0.f,0.f};
  #pragma unroll
  for (int kb = 0; kb < 2; ++kb){
    bf16x8 a[4], bfr;
    #pragma unroll
    for (int mf = 0; mf < 4; ++mf){
      int row = mf*16 + (l & 15);
      int byte = (row << 7) + kb*64 + ((l >> 4) << 4);
      byte ^= (row & 7) << 4;
      a[mf] = *(const bf16x8*)(sRin + byte);
    }
    bfr = *(const bf16x8*)(Wc_pk + ((size_t)(wn*2 + kb)*64 + l)*8);
    #pragma unroll
    for (int mf = 0; mf < 4; ++mf)
      acc2[mf] = __builtin_amdgcn_mfma_f32_16x16x32_bf16(a[mf], bfr, acc2[mf], 0, 0, 0);
  }
  // dot(lh, rh+bc) reduced over cols -> slog[row]
  {
    int col = wn*16 + (l & 15);
    float bcv = bc[col];
    #pragma unroll
    for (int mf = 0; mf < 4; ++mf)
      #pragma unroll
      for (int r = 0; r < 4; ++r){
        int row = mf*16 + ((l >> 4) << 2) + r;
        float v = (acc2[mf][r] + bcv) * bf2f(sL[row*64 + col]);
        v += __shfl_xor(v, 1); v += __shfl_xor(v, 2);
        v += __shfl_xor(v, 4); v += __shfl_xor(v, 8);
        if ((l & 15) == 0) atomicAdd(&slog[row], v);
      }
  }
  __syncthreads();
  if (tid < 64){
    int e = e0 + tid;
    if (e < N_EDGES){
      float p = slog[tid];
      logits[e] = p;
      atomicMax(&segmax[src[e]], ford(p));
    }
  }
}

// ---------------- softmax + aggregation passes ----------------
__global__ void k_passB(const float* __restrict__ logits_in, float* __restrict__ ex_out,
                        const unsigned* __restrict__ segmax, const int* __restrict__ src,
                        float* __restrict__ denom){
  int e = blockIdx.x*256 + threadIdx.x;
  if (e >= N_EDGES) return;
  int s = src[e];
  float ex = __expf(logits_in[e] - funord(segmax[s]));
  ex_out[e] = ex;
  atomicAdd(&denom[s], ex);
}

__global__ void k_passC(const float* __restrict__ ex, const float* __restrict__ denom,
                        const int* __restrict__ src, const int* __restrict__ dst,
                        const float* __restrict__ node_score, float* __restrict__ nns){
  int e = blockIdx.x*256 + threadIdx.x;
  if (e >= N_EDGES) return;
  int s = src[e];
  float tr = ex[e] / denom[s];
  atomicAdd(&nns[dst[e]], tr * node_score[s]);
}

__global__ void k_passD(const float* __restrict__ nns, const int* __restrict__ ent,
                        float* __restrict__ out){
  int v = blockIdx.x*256 + threadIdx.x;
  if (v >= N_NODES) return;
  atomicAdd(&out[ent[v]], nns[v]);
}

// ---------------- host ----------------
extern "C" void kernel_launch(void* const* d_in, const int* in_sizes, int n_in,
                              void* d_out, int out_size, void* d_ws, size_t ws_size,
                              hipStream_t stream){
  const float* mem   = (const float*)d_in[0];
  const float* nsc   = (const float*)d_in[1];
  const float* relE  = (const float*)d_in[2];
  const float* qsrc  = (const float*)d_in[3];
  const float* qrel  = (const float*)d_in[4];
  const int*   eg    = (const int*)d_in[5];
  const int*   src   = (const int*)d_in[6];
  const int*   dst   = (const int*)d_in[7];
  const int*   ent   = (const int*)d_in[8];
  const float* Wp    = (const float*)d_in[9];
  const float* bp    = (const float*)d_in[10];
  const float* Ws    = (const float*)d_in[11];
  const float* bs    = (const float*)d_in[12];
  const float* Wbs   = (const float*)d_in[13];
  const float* bbs   = (const float*)d_in[14];
  const float* Wl    = (const float*)d_in[15];
  const float* bl    = (const float*)d_in[16];
  const float* Wr    = (const float*)d_in[17];
  const float* br    = (const float*)d_in[18];
  const float* Wc    = (const float*)d_in[19];
  const float* bc    = (const float*)d_in[20];
  float* out = (float*)d_out;

  char* w = (char*)d_ws;
  auto alloc = [&](size_t bytes)->void*{
    void* p = (void*)w; w += (bytes + 255) & ~(size_t)255; return p;
  };
  float* Wnlr = (float*)alloc(32768*4);
  float* Wrlr = (float*)alloc(32768*4);
  unsigned short* Wbs_pk = (unsigned short*)alloc(65536*2);
  unsigned short* Wn_pk  = (unsigned short*)alloc(32768*2);
  unsigned short* Wr_pk  = (unsigned short*)alloc(32768*2);
  unsigned short* Wc_pk  = (unsigned short*)alloc(4096*2);
  float* cv  = (float*)alloc(256*4);
  float* qs  = (float*)alloc((size_t)N_Q*SSM*4);
  float* qr  = (float*)alloc((size_t)N_Q*DSM*4);
  float* qctx_l = (float*)alloc((size_t)N_Q*DSM*4);
  float* qctx_r = (float*)alloc((size_t)N_Q*DSM*4);
  unsigned short* node_l = (unsigned short*)alloc((size_t)N_NODES*64*2);
  unsigned short* node_r = (unsigned short*)alloc((size_t)N_NODES*64*2);
  float* logits = (float*)alloc((size_t)N_EDGES*4);
  float* exbuf  = (float*)alloc((size_t)N_EDGES*4);
  unsigned* segmax = (unsigned*)alloc((size_t)N_NODES*4);
  float* denom = (float*)alloc((size_t)N_NODES*4);
  float* nns   = (float*)alloc((size_t)N_NODES*4);

  k_init<<<(N_NODES+255)/256, 256, 0, stream>>>(out, segmax, denom, nns);
  k_fold<<<256, 256, 0, stream>>>(Wp, Wl, Wr, Wnlr, Wrlr);
  k_foldb<<<1, 256, 0, stream>>>(bp, Wl, Wr, cv);
  k_qproj<<<48, 256, 0, stream>>>(qsrc, Ws, bs, qrel, Wp, bp, qs, qr);
  k_qctx<<<64, 256, 0, stream>>>(qs, qr, Wl, bl, Wr, br, qctx_l, qctx_r);
  k_pack<<<32, 256, 0, stream>>>(Wbs,  Wbs_pk, 256, 256, 8192);
  k_pack<<<16, 256, 0, stream>>>(Wnlr, Wn_pk,  256, 128, 4096);
  k_pack<<<16, 256, 0, stream>>>(Wrlr, Wr_pk,  256, 128, 4096);
  k_pack<<<2, 256, 0, stream>>>(Wc,   Wc_pk,  64,  64,  512);

  k_node<<<N_NODES/64, 256, 0, stream>>>(mem, Wbs_pk, bbs, Wn_pk, cv, node_l, node_r);
  k_edge<<<(N_EDGES+63)/64, 256, 0, stream>>>(relE, Wr_pk, Wc_pk, cv, bc,
                                              node_l, node_r, qctx_l, qctx_r,
                                              src, dst, eg, logits, segmax);
  k_passB<<<(N_EDGES+255)/256, 256, 0, stream>>>(logits, exbuf, segmax, src, denom);
  k_passC<<<(N_EDGES+255)/256, 256, 0, stream>>>(exbuf, denom, src, dst, nsc, nns);
  k_passD<<<(N_NODES+255)/256, 256, 0, stream>>>(nns, ent, out);
}

// Round 3
// 327.535 us; speedup vs baseline: 4.5616x; 1.1216x over previous
//
#include <hip/hip_runtime.h>
#include <hip/hip_bf16.h>

#define N_NODES 200000
#define N_EDGES 300000
#define N_Q     128
#define N_ENT   50000
#define D       256
#define DSM     64
#define SDIM    128
#define SSM     32

typedef __attribute__((ext_vector_type(8))) short bf16x8;
typedef __attribute__((ext_vector_type(4))) float f32x4;

__device__ __forceinline__ float leaky(float x){ return x > 0.f ? x : 0.01f*x; }

__device__ __forceinline__ unsigned ford(float f){
  unsigned u = __float_as_uint(f);
  return (u & 0x80000000u) ? ~u : (u | 0x80000000u);
}
__device__ __forceinline__ float funord(unsigned u){
  unsigned b = (u & 0x80000000u) ? (u & 0x7FFFFFFFu) : ~u;
  return __uint_as_float(b);
}
__device__ __forceinline__ unsigned short f2bf(float f){
  __hip_bfloat16 h = __float2bfloat16(f);
  return *reinterpret_cast<unsigned short*>(&h);
}
__device__ __forceinline__ unsigned pk2bf(float a, float b){
  float2 t; t.x = a; t.y = b;
  __hip_bfloat162 h = __float22bfloat162_rn(t);
  return *reinterpret_cast<unsigned*>(&h);
}
__device__ __forceinline__ float bf2f(unsigned short h){
  return __uint_as_float(((unsigned)h) << 16);
}

// pack fp32 [K][N] row-major -> bf16 MFMA B-fragment order.
__device__ __forceinline__ void dev_pack(const float* __restrict__ src,
                                         unsigned short* __restrict__ dst,
                                         int K, int N, int id, int total){
  if (id >= total) return;
  int lane = id & 63, fb = id >> 6;
  int KB = K >> 5;
  int kb = fb % KB, nb = fb / KB;
  int k0 = kb*32 + ((lane>>4)<<3);
  int n  = nb*16 + (lane & 15);
  #pragma unroll
  for (int i = 0; i < 8; ++i) dst[(size_t)id*8 + i] = f2bf(src[(size_t)(k0+i)*N + n]);
}

// ---------------- fused setup stage 1 ----------------
// blocks: [0,782) init | [782,1038) fold | 1038 foldb | [1039,1087) qproj |
//         [1087,1119) pack Wbs | [1119,1121) pack Wc
__global__ void k_setup1(float* out, unsigned* segmax, float* denom, float* nns,
                         const float* __restrict__ Wp, const float* __restrict__ Wl,
                         const float* __restrict__ Wr, float* Wnlr, float* Wrlr,
                         const float* __restrict__ bp, float* cv,
                         const float* __restrict__ qsrc, const float* __restrict__ Ws,
                         const float* __restrict__ bs, const float* __restrict__ qrel,
                         float* qs, float* qr,
                         const float* __restrict__ Wbs, unsigned short* Wbs_pk,
                         const float* __restrict__ Wc, unsigned short* Wc_pk){
  int b = blockIdx.x, tid = threadIdx.x;
  if (b < 782){
    int id = b*256 + tid;
    if (id < N_ENT) out[id] = 0.f;
    if (id < N_NODES){ segmax[id] = 0u; denom[id] = 0.f; nns[id] = 0.f; }
  } else if (b < 1038){
    int id = (b-782)*256 + tid;
    int m = id >> 14, rem = id & 16383, k = rem >> 6, c = rem & 63;
    const float* Wsrc = (m & 1) ? Wr : Wl;
    int roff = (m >> 1) * 64;
    float s = 0.f;
    for (int i = 0; i < 64; ++i) s += Wp[k*64+i] * Wsrc[(roff+i)*64 + c];
    float* o = (m >> 1) ? Wrlr : Wnlr;
    o[k*128 + (m&1)*64 + c] = s;
  } else if (b == 1038){
    int m = tid >> 6, c = tid & 63;
    const float* Wsrc = (m & 1) ? Wr : Wl;
    int roff = (m >> 1) * 64;
    float s = 0.f;
    for (int i = 0; i < 64; ++i) s += bp[i] * Wsrc[(roff+i)*64 + c];
    cv[tid] = s;
  } else if (b < 1087){
    int id = (b-1039)*256 + tid;
    if (id < N_Q*SSM){
      int q = id >> 5, i = id & 31;
      float s = bs[i];
      for (int j = 0; j < SDIM; ++j) s += qsrc[q*SDIM+j] * Ws[j*SSM+i];
      qs[id] = s;
    } else {
      int id2 = id - N_Q*SSM;
      int q = id2 >> 6, i = id2 & 63;
      float s = bp[i];
      for (int j = 0; j < D; ++j) s += qrel[q*D+j] * Wp[j*DSM+i];
      qr[id2] = s;
    }
  } else if (b < 1119){
    dev_pack(Wbs, Wbs_pk, 256, 256, (b-1087)*256 + tid, 8192);
  } else {
    dev_pack(Wc, Wc_pk, 64, 64, (b-1119)*256 + tid, 512);
  }
}

// ---------------- fused setup stage 2 ----------------
// blocks: [0,64) qctx | [64,80) pack Wnlr | [80,96) pack Wrlr
__global__ void k_setup2(const float* __restrict__ qs, const float* __restrict__ qr,
                         const float* __restrict__ Wl, const float* __restrict__ bl,
                         const float* __restrict__ Wr, const float* __restrict__ br,
                         float* qctx_l, float* qctx_r,
                         const float* __restrict__ Wnlr, unsigned short* Wn_pk,
                         const float* __restrict__ Wrlr, unsigned short* Wr_pk){
  int b = blockIdx.x, tid = threadIdx.x;
  if (b < 64){
    int id = b*256 + tid;
    int side = id >> 13, rem = id & 8191, q = rem >> 6, c = rem & 63;
    const float* W = side ? Wr : Wl;
    const float* bias = side ? br : bl;
    float s = bias[c];
    for (int i = 0; i < SSM; ++i) s += qs[q*SSM+i] * W[(128+i)*64+c];
    for (int i = 0; i < DSM; ++i) s += qr[q*DSM+i] * W[(160+i)*64+c];
    (side ? qctx_r : qctx_l)[rem] = s;
  } else if (b < 80){
    dev_pack(Wnlr, Wn_pk, 256, 128, (b-64)*256 + tid, 4096);
  } else {
    dev_pack(Wrlr, Wr_pk, 256, 128, (b-80)*256 + tid, 4096);
  }
}

// ---------------- node pipeline (MFMA) ----------------
__global__ __launch_bounds__(256) void k_node(const float* __restrict__ A,
    const unsigned short* __restrict__ Wbs_pk, const float* __restrict__ bbs,
    const unsigned short* __restrict__ Wn_pk, const float* __restrict__ cv,
    unsigned short* __restrict__ node_l, unsigned short* __restrict__ node_r){
  __shared__ char smem[32768];
  int tid = threadIdx.x;
  int row0 = blockIdx.x * 64;                      // 3125*64 == 200000
  {
    const float4* Ag = (const float4*)(A + (size_t)row0 * 256);
    #pragma unroll
    for (int it = 0; it < 16; ++it){
      int f = tid + 256*it;
      int r = f >> 6, c4 = f & 63;
      float4 v = Ag[f];
      uint2 u;
      u.x = pk2bf(v.x, v.y);
      u.y = pk2bf(v.z, v.w);
      int byte = (r << 9) + (c4 << 3);
      byte ^= (r & 7) << 4;
      *(uint2*)(smem + byte) = u;
    }
  }
  __syncthreads();
  int l = tid & 63, wn = tid >> 6;
  f32x4 acc[4][4];
  #pragma unroll
  for (int mf = 0; mf < 4; ++mf)
    #pragma unroll
    for (int nf = 0; nf < 4; ++nf) acc[mf][nf] = (f32x4){0.f,0.f,0.f,0.f};
  for (int kb = 0; kb < 8; ++kb){
    bf16x8 a[4], b[4];
    #pragma unroll
    for (int mf = 0; mf < 4; ++mf){
      int row = mf*16 + (l & 15);
      int byte = (row << 9) + kb*64 + ((l >> 4) << 4);
      byte ^= (row & 7) << 4;
      a[mf] = *(const bf16x8*)(smem + byte);
    }
    #pragma unroll
    for (int nf = 0; nf < 4; ++nf){
      int nb = wn*4 + nf;
      b[nf] = *(const bf16x8*)(Wbs_pk + ((size_t)(nb*8 + kb)*64 + l)*8);
    }
    #pragma unroll
    for (int mf = 0; mf < 4; ++mf)
      #pragma unroll
      for (int nf = 0; nf < 4; ++nf)
        acc[mf][nf] = __builtin_amdgcn_mfma_f32_16x16x32_bf16(a[mf], b[nf], acc[mf][nf], 0, 0, 0);
  }
  __syncthreads();
  #pragma unroll
  for (int mf = 0; mf < 4; ++mf)
    #pragma unroll
    for (int nf = 0; nf < 4; ++nf){
      int col = wn*64 + nf*16 + (l & 15);
      float bb = bbs[col];
      #pragma unroll
      for (int r = 0; r < 4; ++r){
        int row = mf*16 + ((l >> 4) << 2) + r;
        int byte = (row << 9) + col*2;
        byte ^= (row & 7) << 4;
        *(unsigned short*)(smem + byte) = f2bf(leaky(acc[mf][nf][r] + bb));
      }
    }
  __syncthreads();
  f32x4 acc2[4][2];
  #pragma unroll
  for (int mf = 0; mf < 4; ++mf){ acc2[mf][0] = (f32x4){0.f,0.f,0.f,0.f}; acc2[mf][1] = (f32x4){0.f,0.f,0.f,0.f}; }
  for (int kb = 0; kb < 8; ++kb){
    bf16x8 a[4], b[2];
    #pragma unroll
    for (int mf = 0; mf < 4; ++mf){
      int row = mf*16 + (l & 15);
      int byte = (row << 9) + kb*64 + ((l >> 4) << 4);
      byte ^= (row & 7) << 4;
      a[mf] = *(const bf16x8*)(smem + byte);
    }
    #pragma unroll
    for (int nf = 0; nf < 2; ++nf){
      int nb = wn*2 + nf;
      b[nf] = *(const bf16x8*)(Wn_pk + ((size_t)(nb*8 + kb)*64 + l)*8);
    }
    #pragma unroll
    for (int mf = 0; mf < 4; ++mf)
      #pragma unroll
      for (int nf = 0; nf < 2; ++nf)
        acc2[mf][nf] = __builtin_amdgcn_mfma_f32_16x16x32_bf16(a[mf], b[nf], acc2[mf][nf], 0, 0, 0);
  }
  #pragma unroll
  for (int mf = 0; mf < 4; ++mf)
    #pragma unroll
    for (int nf = 0; nf < 2; ++nf){
      int col = wn*32 + nf*16 + (l & 15);
      float cc = cv[col];
      #pragma unroll
      for (int r = 0; r < 4; ++r){
        int row = mf*16 + ((l >> 4) << 2) + r;
        unsigned short h = f2bf(acc2[mf][nf][r] + cc);
        size_t g = (size_t)(row0 + row);
        if (col < 64) node_l[g*64 + col] = h;
        else          node_r[g*64 + col - 64] = h;
      }
    }
}

// ---------------- fused rel + edge scoring (MFMA) ----------------
__global__ __launch_bounds__(256) void k_edge(const float* __restrict__ relE,
    const unsigned short* __restrict__ Wr_pk, const unsigned short* __restrict__ Wc_pk,
    const float* __restrict__ cv, const float* __restrict__ bc,
    const unsigned short* __restrict__ node_l, const unsigned short* __restrict__ node_r,
    const float* __restrict__ qctx_l, const float* __restrict__ qctx_r,
    const int* __restrict__ src, const int* __restrict__ dst, const int* __restrict__ eg,
    float* __restrict__ logits, unsigned* __restrict__ segmax){
  __shared__ char smem[33024];
  unsigned short* sRL  = (unsigned short*)smem;             // [64][128] swz (row&12)<<3
  char*           sLc  = smem + 16384;                      // [64][64] swz (row&12)<<3
  char*           sRin = smem + 24576;                      // [64][64] swz (row&7)<<4
  float*          slog = (float*)(smem + 32768);            // [64]
  int tid = threadIdx.x;
  int e0 = blockIdx.x * 64;
  int l = tid & 63, wn = tid >> 6;

  // index load: lanes 0-15 src, 16-31 dst, 32-47 eg (for this wave's 16 edges)
  int idxv;
  {
    int j = l & 15;
    int e = e0 + wn*16 + j;
    int ec = e < N_EDGES ? e : N_EDGES-1;
    const int* p = (l < 16) ? src : (l < 32) ? dst : eg;
    idxv = p[ec];
  }
  // stage rel_emb [64][256] bf16 swizzled
  {
    const float4* Rg = (const float4*)relE;
    #pragma unroll
    for (int it = 0; it < 16; ++it){
      int f = tid + 256*it;
      int r = f >> 6, c4 = f & 63;
      int ge = e0 + r;
      float4 v = make_float4(0.f,0.f,0.f,0.f);
      if (ge < N_EDGES) v = Rg[(size_t)ge*64 + c4];
      uint2 u;
      u.x = pk2bf(v.x, v.y);
      u.y = pk2bf(v.z, v.w);
      int byte = (r << 9) + (c4 << 3);
      byte ^= (r & 7) << 4;
      *(uint2*)(smem + byte) = u;
    }
  }
  // prefetch node gathers (stay in flight across the barrier, drain under GEMM1)
  unsigned short nlv[16], nrv[16];
  #pragma unroll
  for (int j = 0; j < 16; ++j){
    int s  = __shfl(idxv, j);
    int d2 = __shfl(idxv, 16 + j);
    nlv[j] = node_l[(size_t)s*64 + l];
    nrv[j] = node_r[(size_t)d2*64 + l];
  }
  // barrier that waits LDS writes only (vmcnt left open)
  asm volatile("s_waitcnt lgkmcnt(0)" ::: "memory");
  __builtin_amdgcn_s_barrier();
  __builtin_amdgcn_sched_barrier(0);

  // GEMM1: rel_lr[64][128] = tile @ Wrlr ; wave wn covers cols [wn*32, +32)
  f32x4 acc[4][2];
  #pragma unroll
  for (int mf = 0; mf < 4; ++mf){ acc[mf][0] = (f32x4){0.f,0.f,0.f,0.f}; acc[mf][1] = (f32x4){0.f,0.f,0.f,0.f}; }
  for (int kb = 0; kb < 8; ++kb){
    bf16x8 a[4], b[2];
    #pragma unroll
    for (int mf = 0; mf < 4; ++mf){
      int row = mf*16 + (l & 15);
      int byte = (row << 9) + kb*64 + ((l >> 4) << 4);
      byte ^= (row & 7) << 4;
      a[mf] = *(const bf16x8*)(smem + byte);
    }
    #pragma unroll
    for (int nf = 0; nf < 2; ++nf){
      int nb = wn*2 + nf;
      b[nf] = *(const bf16x8*)(Wr_pk + ((size_t)(nb*8 + kb)*64 + l)*8);
    }
    #pragma unroll
    for (int mf = 0; mf < 4; ++mf)
      #pragma unroll
      for (int nf = 0; nf < 2; ++nf)
        acc[mf][nf] = __builtin_amdgcn_mfma_f32_16x16x32_bf16(a[mf], b[nf], acc[mf][nf], 0, 0, 0);
  }
  __syncthreads();
  // epilogue 1: + cv(rel) -> sRL bf16 [64][128], swizzle (row&12)<<3
  #pragma unroll
  for (int mf = 0; mf < 4; ++mf)
    #pragma unroll
    for (int nf = 0; nf < 2; ++nf){
      int col = wn*32 + nf*16 + (l & 15);
      float cc = cv[128 + col];
      #pragma unroll
      for (int r = 0; r < 4; ++r){
        int row = mf*16 + ((l >> 4) << 2) + r;
        int byte = (row << 8) + (col << 1);
        byte ^= (row & 12) << 3;
        *(unsigned short*)((char*)sRL + byte) = f2bf(acc[mf][nf][r] + cc);
      }
    }
  if (tid < 64) slog[tid] = 0.f;
  __syncthreads();
  // compose: wave wn handles edges [wn*16, +16); gathers already in registers
  #pragma unroll
  for (int j = 0; j < 16; ++j){
    int er = wn*16 + j;
    int e = e0 + er;
    int byteL = (er << 8) + (l << 1);    byteL ^= (er & 12) << 3;          // sRL left
    int byteR = (er << 8) + ((64+l) << 1); byteR ^= (er & 12) << 3;        // sRL right
    int bL = (er << 7) + (l << 1);       bL ^= (er & 12) << 3;             // sL
    int bR = (er << 7) + (l << 1);       bR ^= (er & 7) << 4;              // sRin
    unsigned short lh16 = 0, rr16 = 0;
    if (e < N_EDGES){
      int b = __shfl(idxv, 32 + j);
      float lh = leaky(bf2f(nlv[j]) + bf2f(*(unsigned short*)((char*)sRL + byteL)) + qctx_l[b*64 + l]);
      float rr = leaky(bf2f(nrv[j]) + bf2f(*(unsigned short*)((char*)sRL + byteR)) + qctx_r[b*64 + l]);
      lh16 = f2bf(lh); rr16 = f2bf(rr);
    }
    *(unsigned short*)(sLc + bL) = lh16;
    *(unsigned short*)(sRin + bR) = rr16;
  }
  __syncthreads();
  // GEMM2: RH[64][64] = sRin @ Wc ; wave wn covers cols [wn*16, +16)
  f32x4 acc2[4];
  #pragma unroll
  for (int mf = 0; mf < 4; ++mf) acc2[mf] = (f32x4){0.f,0.f,0.f,0.f};
  #pragma unroll
  for (int kb = 0; kb < 2; ++kb){
    bf16x8 a[4], bfr;
    #pragma unroll
    for (int mf = 0; mf < 4; ++mf){
      int row = mf*16 + (l & 15);
      int byte = (row << 7) + kb*64 + ((l >> 4) << 4);
      byte ^= (row & 7) << 4;
      a[mf] = *(const bf16x8*)(sRin + byte);
    }
    bfr = *(const bf16x8*)(Wc_pk + ((size_t)(wn*2 + kb)*64 + l)*8);
    #pragma unroll
    for (int mf = 0; mf < 4; ++mf)
      acc2[mf] = __builtin_amdgcn_mfma_f32_16x16x32_bf16(a[mf], bfr, acc2[mf], 0, 0, 0);
  }
  // dot(lh, rh+bc) reduced over cols -> slog[row]
  {
    int col = wn*16 + (l & 15);
    float bcv = bc[col];
    #pragma unroll
    for (int mf = 0; mf < 4; ++mf)
      #pragma unroll
      for (int r = 0; r < 4; ++r){
        int row = mf*16 + ((l >> 4) << 2) + r;
        int byte = (row << 7) + (col << 1);
        byte ^= (row & 12) << 3;
        float v = (acc2[mf][r] + bcv) * bf2f(*(unsigned short*)(sLc + byte));
        v += __shfl_xor(v, 1); v += __shfl_xor(v, 2);
        v += __shfl_xor(v, 4); v += __shfl_xor(v, 8);
        if ((l & 15) == 0) atomicAdd(&slog[row], v);
      }
  }
  __syncthreads();
  if (tid < 64){
    int e = e0 + tid;
    if (e < N_EDGES){
      float p = slog[tid];
      logits[e] = p;
      atomicMax(&segmax[src[e]], ford(p));
    }
  }
}

// ---------------- softmax + aggregation passes ----------------
__global__ void k_passB(const float* __restrict__ logits_in, float* __restrict__ ex_out,
                        const unsigned* __restrict__ segmax, const int* __restrict__ src,
                        float* __restrict__ denom){
  int e = blockIdx.x*256 + threadIdx.x;
  if (e >= N_EDGES) return;
  int s = src[e];
  float ex = __expf(logits_in[e] - funord(segmax[s]));
  ex_out[e] = ex;
  atomicAdd(&denom[s], ex);
}

__global__ void k_passC(const float* __restrict__ ex, const float* __restrict__ denom,
                        const int* __restrict__ src, const int* __restrict__ dst,
                        const float* __restrict__ node_score, float* __restrict__ nns){
  int e = blockIdx.x*256 + threadIdx.x;
  if (e >= N_EDGES) return;
  int s = src[e];
  float tr = ex[e] / denom[s];
  atomicAdd(&nns[dst[e]], tr * node_score[s]);
}

__global__ void k_passD(const float* __restrict__ nns, const int* __restrict__ ent,
                        float* __restrict__ out){
  int v = blockIdx.x*256 + threadIdx.x;
  if (v >= N_NODES) return;
  atomicAdd(&out[ent[v]], nns[v]);
}

// ---------------- host ----------------
extern "C" void kernel_launch(void* const* d_in, const int* in_sizes, int n_in,
                              void* d_out, int out_size, void* d_ws, size_t ws_size,
                              hipStream_t stream){
  const float* mem   = (const float*)d_in[0];
  const float* nsc   = (const float*)d_in[1];
  const float* relE  = (const float*)d_in[2];
  const float* qsrc  = (const float*)d_in[3];
  const float* qrel  = (const float*)d_in[4];
  const int*   eg    = (const int*)d_in[5];
  const int*   src   = (const int*)d_in[6];
  const int*   dst   = (const int*)d_in[7];
  const int*   ent   = (const int*)d_in[8];
  const float* Wp    = (const float*)d_in[9];
  const float* bp    = (const float*)d_in[10];
  const float* Ws    = (const float*)d_in[11];
  const float* bs    = (const float*)d_in[12];
  const float* Wbs   = (const float*)d_in[13];
  const float* bbs   = (const float*)d_in[14];
  const float* Wl    = (const float*)d_in[15];
  const float* bl    = (const float*)d_in[16];
  const float* Wr    = (const float*)d_in[17];
  const float* br    = (const float*)d_in[18];
  const float* Wc    = (const float*)d_in[19];
  const float* bc    = (const float*)d_in[20];
  float* out = (float*)d_out;

  char* w = (char*)d_ws;
  auto alloc = [&](size_t bytes)->void*{
    void* p = (void*)w; w += (bytes + 255) & ~(size_t)255; return p;
  };
  float* Wnlr = (float*)alloc(32768*4);
  float* Wrlr = (float*)alloc(32768*4);
  unsigned short* Wbs_pk = (unsigned short*)alloc(65536*2);
  unsigned short* Wn_pk  = (unsigned short*)alloc(32768*2);
  unsigned short* Wr_pk  = (unsigned short*)alloc(32768*2);
  unsigned short* Wc_pk  = (unsigned short*)alloc(4096*2);
  float* cv  = (float*)alloc(256*4);
  float* qs  = (float*)alloc((size_t)N_Q*SSM*4);
  float* qr  = (float*)alloc((size_t)N_Q*DSM*4);
  float* qctx_l = (float*)alloc((size_t)N_Q*DSM*4);
  float* qctx_r = (float*)alloc((size_t)N_Q*DSM*4);
  unsigned short* node_l = (unsigned short*)alloc((size_t)N_NODES*64*2);
  unsigned short* node_r = (unsigned short*)alloc((size_t)N_NODES*64*2);
  float* logits = (float*)alloc((size_t)N_EDGES*4);
  float* exbuf  = (float*)alloc((size_t)N_EDGES*4);
  unsigned* segmax = (unsigned*)alloc((size_t)N_NODES*4);
  float* denom = (float*)alloc((size_t)N_NODES*4);
  float* nns   = (float*)alloc((size_t)N_NODES*4);

  k_setup1<<<1121, 256, 0, stream>>>(out, segmax, denom, nns,
                                     Wp, Wl, Wr, Wnlr, Wrlr, bp, cv,
                                     qsrc, Ws, bs, qrel, qs, qr,
                                     Wbs, Wbs_pk, Wc, Wc_pk);
  k_setup2<<<96, 256, 0, stream>>>(qs, qr, Wl, bl, Wr, br, qctx_l, qctx_r,
                                   Wnlr, Wn_pk, Wrlr, Wr_pk);
  k_node<<<N_NODES/64, 256, 0, stream>>>(mem, Wbs_pk, bbs, Wn_pk, cv, node_l, node_r);
  k_edge<<<(N_EDGES+63)/64, 256, 0, stream>>>(relE, Wr_pk, Wc_pk, cv, bc,
                                              node_l, node_r, qctx_l, qctx_r,
                                              src, dst, eg, logits, segmax);
  k_passB<<<(N_EDGES+255)/256, 256, 0, stream>>>(logits, exbuf, segmax, src, denom);
  k_passC<<<(N_EDGES+255)/256, 256, 0, stream>>>(exbuf, denom, src, dst, nsc, nns);
  k_passD<<<(N_NODES+255)/256, 256, 0, stream>>>(nns, ent, out);
}

// Round 4
// 324.696 us; speedup vs baseline: 4.6015x; 1.0087x over previous
//
#include <hip/hip_runtime.h>
#include <hip/hip_bf16.h>

#define N_NODES 200000
#define N_EDGES 300000
#define N_Q     128
#define N_ENT   50000
#define D       256
#define DSM     64
#define SDIM    128
#define SSM     32

typedef __attribute__((ext_vector_type(8))) short bf16x8;
typedef __attribute__((ext_vector_type(4))) float f32x4;

__device__ __forceinline__ float leaky(float x){ return x > 0.f ? x : 0.01f*x; }

__device__ __forceinline__ unsigned short f2bf(float f){
  __hip_bfloat16 h = __float2bfloat16(f);
  return *reinterpret_cast<unsigned short*>(&h);
}
__device__ __forceinline__ unsigned pk2bf(float a, float b){
  float2 t; t.x = a; t.y = b;
  __hip_bfloat162 h = __float22bfloat162_rn(t);
  return *reinterpret_cast<unsigned*>(&h);
}
__device__ __forceinline__ float bf2f(unsigned short h){
  return __uint_as_float(((unsigned)h) << 16);
}

// pack fp32 [K][N] row-major -> bf16 MFMA B-fragment order.
__device__ __forceinline__ void dev_pack(const float* __restrict__ src,
                                         unsigned short* __restrict__ dst,
                                         int K, int N, int id, int total){
  if (id >= total) return;
  int lane = id & 63, fb = id >> 6;
  int KB = K >> 5;
  int kb = fb % KB, nb = fb / KB;
  int k0 = kb*32 + ((lane>>4)<<3);
  int n  = nb*16 + (lane & 15);
  #pragma unroll
  for (int i = 0; i < 8; ++i) dst[(size_t)id*8 + i] = f2bf(src[(size_t)(k0+i)*N + n]);
}

// ---------------- fused setup stage 1 ----------------
// blocks: [0,782) init | [782,1038) fold | 1038 foldb | [1039,1087) qproj |
//         [1087,1119) pack Wbs | [1119,1121) pack Wc
__global__ void k_setup1(float* out, float* denom,
                         const float* __restrict__ Wp, const float* __restrict__ Wl,
                         const float* __restrict__ Wr, float* Wnlr, float* Wrlr,
                         const float* __restrict__ bp, float* cv,
                         const float* __restrict__ qsrc, const float* __restrict__ Ws,
                         const float* __restrict__ bs, const float* __restrict__ qrel,
                         float* qs, float* qr,
                         const float* __restrict__ Wbs, unsigned short* Wbs_pk,
                         const float* __restrict__ Wc, unsigned short* Wc_pk){
  int b = blockIdx.x, tid = threadIdx.x;
  if (b < 782){
    int id = b*256 + tid;
    if (id < N_ENT) out[id] = 0.f;
    if (id < N_NODES) denom[id] = 0.f;
  } else if (b < 1038){
    int id = (b-782)*256 + tid;
    int m = id >> 14, rem = id & 16383, k = rem >> 6, c = rem & 63;
    const float* Wsrc = (m & 1) ? Wr : Wl;
    int roff = (m >> 1) * 64;
    float s = 0.f;
    for (int i = 0; i < 64; ++i) s += Wp[k*64+i] * Wsrc[(roff+i)*64 + c];
    float* o = (m >> 1) ? Wrlr : Wnlr;
    o[k*128 + (m&1)*64 + c] = s;
  } else if (b == 1038){
    int m = tid >> 6, c = tid & 63;
    const float* Wsrc = (m & 1) ? Wr : Wl;
    int roff = (m >> 1) * 64;
    float s = 0.f;
    for (int i = 0; i < 64; ++i) s += bp[i] * Wsrc[(roff+i)*64 + c];
    cv[tid] = s;
  } else if (b < 1087){
    int id = (b-1039)*256 + tid;
    if (id < N_Q*SSM){
      int q = id >> 5, i = id & 31;
      float s = bs[i];
      for (int j = 0; j < SDIM; ++j) s += qsrc[q*SDIM+j] * Ws[j*SSM+i];
      qs[id] = s;
    } else {
      int id2 = id - N_Q*SSM;
      int q = id2 >> 6, i = id2 & 63;
      float s = bp[i];
      for (int j = 0; j < D; ++j) s += qrel[q*D+j] * Wp[j*DSM+i];
      qr[id2] = s;
    }
  } else if (b < 1119){
    dev_pack(Wbs, Wbs_pk, 256, 256, (b-1087)*256 + tid, 8192);
  } else {
    dev_pack(Wc, Wc_pk, 64, 64, (b-1119)*256 + tid, 512);
  }
}

// ---------------- fused setup stage 2 ----------------
// blocks: [0,32) qctx packed bf16x2 | [32,48) pack Wnlr | [48,64) pack Wrlr
__global__ void k_setup2(const float* __restrict__ qs, const float* __restrict__ qr,
                         const float* __restrict__ Wl, const float* __restrict__ bl,
                         const float* __restrict__ Wr, const float* __restrict__ br,
                         unsigned* qctx_p,
                         const float* __restrict__ Wnlr, unsigned short* Wn_pk,
                         const float* __restrict__ Wrlr, unsigned short* Wr_pk){
  int b = blockIdx.x, tid = threadIdx.x;
  if (b < 32){
    int id = b*256 + tid;                 // 8192 = 128q * 64c
    int q = id >> 6, c = id & 63;
    float sl = bl[c], sr = br[c];
    for (int i = 0; i < SSM; ++i){
      float v = qs[q*SSM+i];
      sl += v * Wl[(128+i)*64+c];
      sr += v * Wr[(128+i)*64+c];
    }
    for (int i = 0; i < DSM; ++i){
      float v = qr[q*DSM+i];
      sl += v * Wl[(160+i)*64+c];
      sr += v * Wr[(160+i)*64+c];
    }
    qctx_p[id] = pk2bf(sl, sr);
  } else if (b < 48){
    dev_pack(Wnlr, Wn_pk, 256, 128, (b-32)*256 + tid, 4096);
  } else {
    dev_pack(Wrlr, Wr_pk, 256, 128, (b-48)*256 + tid, 4096);
  }
}

// ---------------- node pipeline (MFMA) ----------------
__global__ __launch_bounds__(256) void k_node(const float* __restrict__ A,
    const unsigned short* __restrict__ Wbs_pk, const float* __restrict__ bbs,
    const unsigned short* __restrict__ Wn_pk, const float* __restrict__ cv,
    unsigned short* __restrict__ node_l, unsigned short* __restrict__ node_r){
  __shared__ char smem[32768];
  int tid = threadIdx.x;
  int row0 = blockIdx.x * 64;                      // 3125*64 == 200000
  {
    const float4* Ag = (const float4*)(A + (size_t)row0 * 256);
    #pragma unroll
    for (int it = 0; it < 16; ++it){
      int f = tid + 256*it;
      int r = f >> 6, c4 = f & 63;
      float4 v = Ag[f];
      uint2 u;
      u.x = pk2bf(v.x, v.y);
      u.y = pk2bf(v.z, v.w);
      int byte = (r << 9) + (c4 << 3);
      byte ^= (r & 7) << 4;
      *(uint2*)(smem + byte) = u;
    }
  }
  __syncthreads();
  int l = tid & 63, wn = tid >> 6;
  f32x4 acc[4][4];
  #pragma unroll
  for (int mf = 0; mf < 4; ++mf)
    #pragma unroll
    for (int nf = 0; nf < 4; ++nf) acc[mf][nf] = (f32x4){0.f,0.f,0.f,0.f};
  for (int kb = 0; kb < 8; ++kb){
    bf16x8 a[4], b[4];
    #pragma unroll
    for (int mf = 0; mf < 4; ++mf){
      int row = mf*16 + (l & 15);
      int byte = (row << 9) + kb*64 + ((l >> 4) << 4);
      byte ^= (row & 7) << 4;
      a[mf] = *(const bf16x8*)(smem + byte);
    }
    #pragma unroll
    for (int nf = 0; nf < 4; ++nf){
      int nb = wn*4 + nf;
      b[nf] = *(const bf16x8*)(Wbs_pk + ((size_t)(nb*8 + kb)*64 + l)*8);
    }
    #pragma unroll
    for (int mf = 0; mf < 4; ++mf)
      #pragma unroll
      for (int nf = 0; nf < 4; ++nf)
        acc[mf][nf] = __builtin_amdgcn_mfma_f32_16x16x32_bf16(a[mf], b[nf], acc[mf][nf], 0, 0, 0);
  }
  __syncthreads();
  #pragma unroll
  for (int mf = 0; mf < 4; ++mf)
    #pragma unroll
    for (int nf = 0; nf < 4; ++nf){
      int col = wn*64 + nf*16 + (l & 15);
      float bb = bbs[col];
      #pragma unroll
      for (int r = 0; r < 4; ++r){
        int row = mf*16 + ((l >> 4) << 2) + r;
        int byte = (row << 9) + col*2;
        byte ^= (row & 7) << 4;
        *(unsigned short*)(smem + byte) = f2bf(leaky(acc[mf][nf][r] + bb));
      }
    }
  __syncthreads();
  f32x4 acc2[4][2];
  #pragma unroll
  for (int mf = 0; mf < 4; ++mf){ acc2[mf][0] = (f32x4){0.f,0.f,0.f,0.f}; acc2[mf][1] = (f32x4){0.f,0.f,0.f,0.f}; }
  for (int kb = 0; kb < 8; ++kb){
    bf16x8 a[4], b[2];
    #pragma unroll
    for (int mf = 0; mf < 4; ++mf){
      int row = mf*16 + (l & 15);
      int byte = (row << 9) + kb*64 + ((l >> 4) << 4);
      byte ^= (row & 7) << 4;
      a[mf] = *(const bf16x8*)(smem + byte);
    }
    #pragma unroll
    for (int nf = 0; nf < 2; ++nf){
      int nb = wn*2 + nf;
      b[nf] = *(const bf16x8*)(Wn_pk + ((size_t)(nb*8 + kb)*64 + l)*8);
    }
    #pragma unroll
    for (int mf = 0; mf < 4; ++mf)
      #pragma unroll
      for (int nf = 0; nf < 2; ++nf)
        acc2[mf][nf] = __builtin_amdgcn_mfma_f32_16x16x32_bf16(a[mf], b[nf], acc2[mf][nf], 0, 0, 0);
  }
  #pragma unroll
  for (int mf = 0; mf < 4; ++mf)
    #pragma unroll
    for (int nf = 0; nf < 2; ++nf){
      int col = wn*32 + nf*16 + (l & 15);
      float cc = cv[col];
      #pragma unroll
      for (int r = 0; r < 4; ++r){
        int row = mf*16 + ((l >> 4) << 2) + r;
        unsigned short h = f2bf(acc2[mf][nf][r] + cc);
        size_t g = (size_t)(row0 + row);
        if (col < 64) node_l[g*64 + col] = h;
        else          node_r[g*64 + col - 64] = h;
      }
    }
}

// ---------------- fused rel + edge scoring (MFMA) ----------------
// 64 edges/block: stage rel tile, GEMM1 rel_lr, compose with prefetched
// node/qctx gathers, GEMM2 rh=R@Wc, dot, then ex=exp(logit) + denom atomics.
__global__ __launch_bounds__(256) void k_edge(const float* __restrict__ relE,
    const unsigned short* __restrict__ Wr_pk, const unsigned short* __restrict__ Wc_pk,
    const float* __restrict__ cv, const float* __restrict__ bc,
    const unsigned short* __restrict__ node_l, const unsigned short* __restrict__ node_r,
    const unsigned* __restrict__ qctx_p,
    const int* __restrict__ src, const int* __restrict__ dst, const int* __restrict__ eg,
    float* __restrict__ exbuf, float* __restrict__ denom){
  __shared__ char smem[33024];
  unsigned short* sRL  = (unsigned short*)smem;             // [64][128] swz (row&12)<<3
  char*           sLc  = smem + 16384;                      // [64][64] swz (row&12)<<3
  char*           sRin = smem + 24576;                      // [64][64] swz (row&7)<<4
  float*          slog = (float*)(smem + 32768);            // [64]
  int tid = threadIdx.x;
  int e0 = blockIdx.x * 64;
  int l = tid & 63, wn = tid >> 6;

  // index load: lanes 0-15 src, 16-31 dst, 32-47 eg (for this wave's 16 edges)
  int idxv;
  {
    int j = l & 15;
    int e = e0 + wn*16 + j;
    int ec = e < N_EDGES ? e : N_EDGES-1;
    const int* p = (l < 16) ? src : (l < 32) ? dst : eg;
    idxv = p[ec];
  }
  // stage rel_emb [64][256] bf16 swizzled
  {
    const float4* Rg = (const float4*)relE;
    #pragma unroll
    for (int it = 0; it < 16; ++it){
      int f = tid + 256*it;
      int r = f >> 6, c4 = f & 63;
      int ge = e0 + r;
      float4 v = make_float4(0.f,0.f,0.f,0.f);
      if (ge < N_EDGES) v = Rg[(size_t)ge*64 + c4];
      uint2 u;
      u.x = pk2bf(v.x, v.y);
      u.y = pk2bf(v.z, v.w);
      int byte = (r << 9) + (c4 << 3);
      byte ^= (r & 7) << 4;
      *(uint2*)(smem + byte) = u;
    }
  }
  // prefetch gathers (stay in flight across the barrier, drain under GEMM1)
  unsigned short nlv[16], nrv[16];
  unsigned qpv[16];
  #pragma unroll
  for (int j = 0; j < 16; ++j){
    int s  = __shfl(idxv, j);
    int d2 = __shfl(idxv, 16 + j);
    int b  = __shfl(idxv, 32 + j);
    nlv[j] = node_l[(size_t)s*64 + l];
    nrv[j] = node_r[(size_t)d2*64 + l];
    qpv[j] = qctx_p[b*64 + l];
  }
  // barrier that waits LDS writes only (vmcnt left open)
  asm volatile("s_waitcnt lgkmcnt(0)" ::: "memory");
  __builtin_amdgcn_s_barrier();
  __builtin_amdgcn_sched_barrier(0);

  // GEMM1: rel_lr[64][128] = tile @ Wrlr ; wave wn covers cols [wn*32, +32)
  f32x4 acc[4][2];
  #pragma unroll
  for (int mf = 0; mf < 4; ++mf){ acc[mf][0] = (f32x4){0.f,0.f,0.f,0.f}; acc[mf][1] = (f32x4){0.f,0.f,0.f,0.f}; }
  for (int kb = 0; kb < 8; ++kb){
    bf16x8 a[4], b[2];
    #pragma unroll
    for (int mf = 0; mf < 4; ++mf){
      int row = mf*16 + (l & 15);
      int byte = (row << 9) + kb*64 + ((l >> 4) << 4);
      byte ^= (row & 7) << 4;
      a[mf] = *(const bf16x8*)(smem + byte);
    }
    #pragma unroll
    for (int nf = 0; nf < 2; ++nf){
      int nb = wn*2 + nf;
      b[nf] = *(const bf16x8*)(Wr_pk + ((size_t)(nb*8 + kb)*64 + l)*8);
    }
    #pragma unroll
    for (int mf = 0; mf < 4; ++mf)
      #pragma unroll
      for (int nf = 0; nf < 2; ++nf)
        acc[mf][nf] = __builtin_amdgcn_mfma_f32_16x16x32_bf16(a[mf], b[nf], acc[mf][nf], 0, 0, 0);
  }
  __syncthreads();
  // epilogue 1: + cv(rel) -> sRL bf16 [64][128], swizzle (row&12)<<3
  #pragma unroll
  for (int mf = 0; mf < 4; ++mf)
    #pragma unroll
    for (int nf = 0; nf < 2; ++nf){
      int col = wn*32 + nf*16 + (l & 15);
      float cc = cv[128 + col];
      #pragma unroll
      for (int r = 0; r < 4; ++r){
        int row = mf*16 + ((l >> 4) << 2) + r;
        int byte = (row << 8) + (col << 1);
        byte ^= (row & 12) << 3;
        *(unsigned short*)((char*)sRL + byte) = f2bf(acc[mf][nf][r] + cc);
      }
    }
  if (tid < 64) slog[tid] = 0.f;
  __syncthreads();
  // compose: wave wn handles edges [wn*16, +16); all gathers already in registers
  #pragma unroll
  for (int j = 0; j < 16; ++j){
    int er = wn*16 + j;
    int e = e0 + er;
    int byteL = (er << 8) + (l << 1);    byteL ^= (er & 12) << 3;          // sRL left
    int byteR = (er << 8) + ((64+l) << 1); byteR ^= (er & 12) << 3;        // sRL right
    int bL = (er << 7) + (l << 1);       bL ^= (er & 12) << 3;             // sLc
    int bR = (er << 7) + (l << 1);       bR ^= (er & 7) << 4;              // sRin
    unsigned short lh16 = 0, rr16 = 0;
    if (e < N_EDGES){
      unsigned qv = qpv[j];
      float ql = bf2f((unsigned short)(qv & 0xFFFFu));
      float qr = bf2f((unsigned short)(qv >> 16));
      float lh = leaky(bf2f(nlv[j]) + bf2f(*(unsigned short*)((char*)sRL + byteL)) + ql);
      float rr = leaky(bf2f(nrv[j]) + bf2f(*(unsigned short*)((char*)sRL + byteR)) + qr);
      lh16 = f2bf(lh); rr16 = f2bf(rr);
    }
    *(unsigned short*)(sLc + bL) = lh16;
    *(unsigned short*)(sRin + bR) = rr16;
  }
  __syncthreads();
  // GEMM2: RH[64][64] = sRin @ Wc ; wave wn covers cols [wn*16, +16)
  f32x4 acc2[4];
  #pragma unroll
  for (int mf = 0; mf < 4; ++mf) acc2[mf] = (f32x4){0.f,0.f,0.f,0.f};
  #pragma unroll
  for (int kb = 0; kb < 2; ++kb){
    bf16x8 a[4], bfr;
    #pragma unroll
    for (int mf = 0; mf < 4; ++mf){
      int row = mf*16 + (l & 15);
      int byte = (row << 7) + kb*64 + ((l >> 4) << 4);
      byte ^= (row & 7) << 4;
      a[mf] = *(const bf16x8*)(sRin + byte);
    }
    bfr = *(const bf16x8*)(Wc_pk + ((size_t)(wn*2 + kb)*64 + l)*8);
    #pragma unroll
    for (int mf = 0; mf < 4; ++mf)
      acc2[mf] = __builtin_amdgcn_mfma_f32_16x16x32_bf16(a[mf], bfr, acc2[mf], 0, 0, 0);
  }
  // dot(lh, rh+bc) reduced over cols -> slog[row]
  {
    int col = wn*16 + (l & 15);
    float bcv = bc[col];
    #pragma unroll
    for (int mf = 0; mf < 4; ++mf)
      #pragma unroll
      for (int r = 0; r < 4; ++r){
        int row = mf*16 + ((l >> 4) << 2) + r;
        int byte = (row << 7) + (col << 1);
        byte ^= (row & 12) << 3;
        float v = (acc2[mf][r] + bcv) * bf2f(*(unsigned short*)(sLc + byte));
        v += __shfl_xor(v, 1); v += __shfl_xor(v, 2);
        v += __shfl_xor(v, 4); v += __shfl_xor(v, 8);
        if ((l & 15) == 0) atomicAdd(&slog[row], v);
      }
  }
  __syncthreads();
  // tail: ex = exp(logit) (no max subtraction needed: |logit| <~ 8), denom atomics.
  // lane j<16 of wave wn owns edge e0+wn*16+j and already holds src in idxv.
  if (l < 16){
    int e = e0 + wn*16 + l;
    if (e < N_EDGES){
      float ex = __expf(slog[wn*16 + l]);
      exbuf[e] = ex;
      atomicAdd(&denom[idxv], ex);
    }
  }
}

// ---------------- final pass: trans + propagate + entity aggregate ----------------
__global__ void k_passC(const float* __restrict__ exbuf, const float* __restrict__ denom,
                        const int* __restrict__ src, const int* __restrict__ dst,
                        const float* __restrict__ node_score, const int* __restrict__ ent,
                        float* __restrict__ out){
  int e = blockIdx.x*256 + threadIdx.x;
  if (e >= N_EDGES) return;
  int s = src[e];
  float tr = exbuf[e] / denom[s];
  atomicAdd(&out[ent[dst[e]]], tr * node_score[s]);
}

// ---------------- host ----------------
extern "C" void kernel_launch(void* const* d_in, const int* in_sizes, int n_in,
                              void* d_out, int out_size, void* d_ws, size_t ws_size,
                              hipStream_t stream){
  const float* mem   = (const float*)d_in[0];
  const float* nsc   = (const float*)d_in[1];
  const float* relE  = (const float*)d_in[2];
  const float* qsrc  = (const float*)d_in[3];
  const float* qrel  = (const float*)d_in[4];
  const int*   eg    = (const int*)d_in[5];
  const int*   src   = (const int*)d_in[6];
  const int*   dst   = (const int*)d_in[7];
  const int*   ent   = (const int*)d_in[8];
  const float* Wp    = (const float*)d_in[9];
  const float* bp    = (const float*)d_in[10];
  const float* Ws    = (const float*)d_in[11];
  const float* bs    = (const float*)d_in[12];
  const float* Wbs   = (const float*)d_in[13];
  const float* bbs   = (const float*)d_in[14];
  const float* Wl    = (const float*)d_in[15];
  const float* bl    = (const float*)d_in[16];
  const float* Wr    = (const float*)d_in[17];
  const float* br    = (const float*)d_in[18];
  const float* Wc    = (const float*)d_in[19];
  const float* bc    = (const float*)d_in[20];
  float* out = (float*)d_out;

  char* w = (char*)d_ws;
  auto alloc = [&](size_t bytes)->void*{
    void* p = (void*)w; w += (bytes + 255) & ~(size_t)255; return p;
  };
  float* Wnlr = (float*)alloc(32768*4);
  float* Wrlr = (float*)alloc(32768*4);
  unsigned short* Wbs_pk = (unsigned short*)alloc(65536*2);
  unsigned short* Wn_pk  = (unsigned short*)alloc(32768*2);
  unsigned short* Wr_pk  = (unsigned short*)alloc(32768*2);
  unsigned short* Wc_pk  = (unsigned short*)alloc(4096*2);
  float* cv  = (float*)alloc(256*4);
  float* qs  = (float*)alloc((size_t)N_Q*SSM*4);
  float* qr  = (float*)alloc((size_t)N_Q*DSM*4);
  unsigned* qctx_p = (unsigned*)alloc((size_t)N_Q*DSM*4);
  unsigned short* node_l = (unsigned short*)alloc((size_t)N_NODES*64*2);
  unsigned short* node_r = (unsigned short*)alloc((size_t)N_NODES*64*2);
  float* exbuf  = (float*)alloc((size_t)N_EDGES*4);
  float* denom = (float*)alloc((size_t)N_NODES*4);

  k_setup1<<<1121, 256, 0, stream>>>(out, denom,
                                     Wp, Wl, Wr, Wnlr, Wrlr, bp, cv,
                                     qsrc, Ws, bs, qrel, qs, qr,
                                     Wbs, Wbs_pk, Wc, Wc_pk);
  k_setup2<<<64, 256, 0, stream>>>(qs, qr, Wl, bl, Wr, br, qctx_p,
                                   Wnlr, Wn_pk, Wrlr, Wr_pk);
  k_node<<<N_NODES/64, 256, 0, stream>>>(mem, Wbs_pk, bbs, Wn_pk, cv, node_l, node_r);
  k_edge<<<(N_EDGES+63)/64, 256, 0, stream>>>(relE, Wr_pk, Wc_pk, cv, bc,
                                              node_l, node_r, qctx_p,
                                              src, dst, eg, exbuf, denom);
  k_passC<<<(N_EDGES+255)/256, 256, 0, stream>>>(exbuf, denom, src, dst, nsc, ent, out);
}

// Round 5
// 275.565 us; speedup vs baseline: 5.4219x; 1.1783x over previous
//
#include <hip/hip_runtime.h>
#include <hip/hip_bf16.h>

#define N_NODES 200000
#define N_EDGES 300000
#define N_Q     128
#define N_ENT   50000
#define D       256
#define DSM     64
#define SDIM    128
#define SSM     32

typedef __attribute__((ext_vector_type(8))) short bf16x8;
typedef __attribute__((ext_vector_type(4))) float f32x4;

__device__ __forceinline__ float leaky(float x){ return x > 0.f ? x : 0.01f*x; }

__device__ __forceinline__ unsigned short f2bf(float f){
  __hip_bfloat16 h = __float2bfloat16(f);
  return *reinterpret_cast<unsigned short*>(&h);
}
__device__ __forceinline__ unsigned pk2bf(float a, float b){
  float2 t; t.x = a; t.y = b;
  __hip_bfloat162 h = __float22bfloat162_rn(t);
  return *reinterpret_cast<unsigned*>(&h);
}
__device__ __forceinline__ float bf2f(unsigned short h){
  return __uint_as_float(((unsigned)h) << 16);
}

// pack fp32 [K][N] row-major -> bf16 MFMA B-fragment order.
__device__ __forceinline__ void dev_pack(const float* __restrict__ src,
                                         unsigned short* __restrict__ dst,
                                         int K, int N, int id, int total){
  if (id >= total) return;
  int lane = id & 63, fb = id >> 6;
  int KB = K >> 5;
  int kb = fb % KB, nb = fb / KB;
  int k0 = kb*32 + ((lane>>4)<<3);
  int n  = nb*16 + (lane & 15);
  #pragma unroll
  for (int i = 0; i < 8; ++i) dst[(size_t)id*8 + i] = f2bf(src[(size_t)(k0+i)*N + n]);
}

// ---------------- fused setup stage 1 ----------------
__global__ void k_setup1(float* out, float* denom,
                         const float* __restrict__ Wp, const float* __restrict__ Wl,
                         const float* __restrict__ Wr, float* Wnlr, float* Wrlr,
                         const float* __restrict__ bp, float* cv,
                         const float* __restrict__ qsrc, const float* __restrict__ Ws,
                         const float* __restrict__ bs, const float* __restrict__ qrel,
                         float* qs, float* qr,
                         const float* __restrict__ Wbs, unsigned short* Wbs_pk,
                         const float* __restrict__ Wc, unsigned short* Wc_pk){
  int b = blockIdx.x, tid = threadIdx.x;
  if (b < 782){
    int id = b*256 + tid;
    if (id < N_ENT) out[id] = 0.f;
    if (id < N_NODES) denom[id] = 0.f;
  } else if (b < 1038){
    int id = (b-782)*256 + tid;
    int m = id >> 14, rem = id & 16383, k = rem >> 6, c = rem & 63;
    const float* Wsrc = (m & 1) ? Wr : Wl;
    int roff = (m >> 1) * 64;
    float s = 0.f;
    for (int i = 0; i < 64; ++i) s += Wp[k*64+i] * Wsrc[(roff+i)*64 + c];
    float* o = (m >> 1) ? Wrlr : Wnlr;
    o[k*128 + (m&1)*64 + c] = s;
  } else if (b == 1038){
    int m = tid >> 6, c = tid & 63;
    const float* Wsrc = (m & 1) ? Wr : Wl;
    int roff = (m >> 1) * 64;
    float s = 0.f;
    for (int i = 0; i < 64; ++i) s += bp[i] * Wsrc[(roff+i)*64 + c];
    cv[tid] = s;
  } else if (b < 1087){
    int id = (b-1039)*256 + tid;
    if (id < N_Q*SSM){
      int q = id >> 5, i = id & 31;
      float s = bs[i];
      for (int j = 0; j < SDIM; ++j) s += qsrc[q*SDIM+j] * Ws[j*SSM+i];
      qs[id] = s;
    } else {
      int id2 = id - N_Q*SSM;
      int q = id2 >> 6, i = id2 & 63;
      float s = bp[i];
      for (int j = 0; j < D; ++j) s += qrel[q*D+j] * Wp[j*DSM+i];
      qr[id2] = s;
    }
  } else if (b < 1119){
    dev_pack(Wbs, Wbs_pk, 256, 256, (b-1087)*256 + tid, 8192);
  } else {
    dev_pack(Wc, Wc_pk, 64, 64, (b-1119)*256 + tid, 512);
  }
}

// ---------------- fused setup stage 2 ----------------
__global__ void k_setup2(const float* __restrict__ qs, const float* __restrict__ qr,
                         const float* __restrict__ Wl, const float* __restrict__ bl,
                         const float* __restrict__ Wr, const float* __restrict__ br,
                         unsigned* qctx_p,
                         const float* __restrict__ Wnlr, unsigned short* Wn_pk,
                         const float* __restrict__ Wrlr, unsigned short* Wr_pk){
  int b = blockIdx.x, tid = threadIdx.x;
  if (b < 32){
    int id = b*256 + tid;                 // 8192 = 128q * 64c
    int q = id >> 6, c = id & 63;
    float sl = bl[c], sr = br[c];
    for (int i = 0; i < SSM; ++i){
      float v = qs[q*SSM+i];
      sl += v * Wl[(128+i)*64+c];
      sr += v * Wr[(128+i)*64+c];
    }
    for (int i = 0; i < DSM; ++i){
      float v = qr[q*DSM+i];
      sl += v * Wl[(160+i)*64+c];
      sr += v * Wr[(160+i)*64+c];
    }
    qctx_p[id] = pk2bf(sl, sr);
  } else if (b < 48){
    dev_pack(Wnlr, Wn_pk, 256, 128, (b-32)*256 + tid, 4096);
  } else {
    dev_pack(Wrlr, Wr_pk, 256, 128, (b-48)*256 + tid, 4096);
  }
}

// ---------------- node pipeline (MFMA) ----------------
__global__ __launch_bounds__(256) void k_node(const float* __restrict__ A,
    const unsigned short* __restrict__ Wbs_pk, const float* __restrict__ bbs,
    const unsigned short* __restrict__ Wn_pk, const float* __restrict__ cv,
    unsigned short* __restrict__ node_l, unsigned short* __restrict__ node_r){
  __shared__ char smem[32768];
  int tid = threadIdx.x;
  int row0 = blockIdx.x * 64;                      // 3125*64 == 200000
  {
    const float4* Ag = (const float4*)(A + (size_t)row0 * 256);
    #pragma unroll
    for (int it = 0; it < 16; ++it){
      int f = tid + 256*it;
      int r = f >> 6, c4 = f & 63;
      float4 v = Ag[f];
      uint2 u;
      u.x = pk2bf(v.x, v.y);
      u.y = pk2bf(v.z, v.w);
      int byte = (r << 9) + (c4 << 3);
      byte ^= (r & 7) << 4;
      *(uint2*)(smem + byte) = u;
    }
  }
  __syncthreads();
  int l = tid & 63, wn = tid >> 6;
  f32x4 acc[4][4];
  #pragma unroll
  for (int mf = 0; mf < 4; ++mf)
    #pragma unroll
    for (int nf = 0; nf < 4; ++nf) acc[mf][nf] = (f32x4){0.f,0.f,0.f,0.f};
  for (int kb = 0; kb < 8; ++kb){
    bf16x8 a[4], b[4];
    #pragma unroll
    for (int mf = 0; mf < 4; ++mf){
      int row = mf*16 + (l & 15);
      int byte = (row << 9) + kb*64 + ((l >> 4) << 4);
      byte ^= (row & 7) << 4;
      a[mf] = *(const bf16x8*)(smem + byte);
    }
    #pragma unroll
    for (int nf = 0; nf < 4; ++nf){
      int nb = wn*4 + nf;
      b[nf] = *(const bf16x8*)(Wbs_pk + ((size_t)(nb*8 + kb)*64 + l)*8);
    }
    #pragma unroll
    for (int mf = 0; mf < 4; ++mf)
      #pragma unroll
      for (int nf = 0; nf < 4; ++nf)
        acc[mf][nf] = __builtin_amdgcn_mfma_f32_16x16x32_bf16(a[mf], b[nf], acc[mf][nf], 0, 0, 0);
  }
  __syncthreads();
  #pragma unroll
  for (int mf = 0; mf < 4; ++mf)
    #pragma unroll
    for (int nf = 0; nf < 4; ++nf){
      int col = wn*64 + nf*16 + (l & 15);
      float bb = bbs[col];
      #pragma unroll
      for (int r = 0; r < 4; ++r){
        int row = mf*16 + ((l >> 4) << 2) + r;
        int byte = (row << 9) + col*2;
        byte ^= (row & 7) << 4;
        *(unsigned short*)(smem + byte) = f2bf(leaky(acc[mf][nf][r] + bb));
      }
    }
  __syncthreads();
  f32x4 acc2[4][2];
  #pragma unroll
  for (int mf = 0; mf < 4; ++mf){ acc2[mf][0] = (f32x4){0.f,0.f,0.f,0.f}; acc2[mf][1] = (f32x4){0.f,0.f,0.f,0.f}; }
  for (int kb = 0; kb < 8; ++kb){
    bf16x8 a[4], b[2];
    #pragma unroll
    for (int mf = 0; mf < 4; ++mf){
      int row = mf*16 + (l & 15);
      int byte = (row << 9) + kb*64 + ((l >> 4) << 4);
      byte ^= (row & 7) << 4;
      a[mf] = *(const bf16x8*)(smem + byte);
    }
    #pragma unroll
    for (int nf = 0; nf < 2; ++nf){
      int nb = wn*2 + nf;
      b[nf] = *(const bf16x8*)(Wn_pk + ((size_t)(nb*8 + kb)*64 + l)*8);
    }
    #pragma unroll
    for (int mf = 0; mf < 4; ++mf)
      #pragma unroll
      for (int nf = 0; nf < 2; ++nf)
        acc2[mf][nf] = __builtin_amdgcn_mfma_f32_16x16x32_bf16(a[mf], b[nf], acc2[mf][nf], 0, 0, 0);
  }
  #pragma unroll
  for (int mf = 0; mf < 4; ++mf)
    #pragma unroll
    for (int nf = 0; nf < 2; ++nf){
      int col = wn*32 + nf*16 + (l & 15);
      float cc = cv[col];
      #pragma unroll
      for (int r = 0; r < 4; ++r){
        int row = mf*16 + ((l >> 4) << 2) + r;
        unsigned short h = f2bf(acc2[mf][nf][r] + cc);
        size_t g = (size_t)(row0 + row);
        if (col < 64) node_l[g*64 + col] = h;
        else          node_r[g*64 + col - 64] = h;
      }
    }
}

// ---------------- fused rel + edge scoring (MFMA) ----------------
// 64 edges/block, LDS exactly 32KB (5 blocks/CU). Wave wn owns edges
// [wn*16, wn*16+16): GEMM2 + logit reduction are fully wave-local (3 barriers).
__global__ __launch_bounds__(256) void k_edge(const float* __restrict__ relE,
    const unsigned short* __restrict__ Wr_pk, const unsigned short* __restrict__ Wc_pk,
    const float* __restrict__ cv, const float* __restrict__ bc,
    const unsigned short* __restrict__ node_l, const unsigned short* __restrict__ node_r,
    const unsigned* __restrict__ qctx_p,
    const int* __restrict__ src, const int* __restrict__ dst, const int* __restrict__ eg,
    float* __restrict__ exbuf, float* __restrict__ denom){
  __shared__ char smem[32768];
  unsigned short* sRL  = (unsigned short*)smem;             // [64][128] swz (row&12)<<3
  char*           sLc  = smem + 16384;                      // [64][64] swz (row&12)<<3
  char*           sRin = smem + 24576;                      // [64][64] swz (row&7)<<4
  int tid = threadIdx.x;
  int e0 = blockIdx.x * 64;
  int l = tid & 63, wn = tid >> 6;

  // index load: lanes 0-15 src, 16-31 dst, 32-47 eg (this wave's 16 edges)
  int idxv;
  {
    int j = l & 15;
    int e = e0 + wn*16 + j;
    int ec = e < N_EDGES ? e : N_EDGES-1;
    const int* p = (l < 16) ? src : (l < 32) ? dst : eg;
    idxv = p[ec];
  }
  // stage rel_emb [64][256] bf16 swizzled (full 32KB)
  {
    const float4* Rg = (const float4*)relE;
    #pragma unroll
    for (int it = 0; it < 16; ++it){
      int f = tid + 256*it;
      int r = f >> 6, c4 = f & 63;
      int ge = e0 + r;
      float4 v = make_float4(0.f,0.f,0.f,0.f);
      if (ge < N_EDGES) v = Rg[(size_t)ge*64 + c4];
      uint2 u;
      u.x = pk2bf(v.x, v.y);
      u.y = pk2bf(v.z, v.w);
      int byte = (r << 9) + (c4 << 3);
      byte ^= (r & 7) << 4;
      *(uint2*)(smem + byte) = u;
    }
  }
  __syncthreads();

  // GEMM1: rel_lr[64][128] = tile @ Wrlr ; wave wn covers cols [wn*32, +32)
  f32x4 acc[4][2];
  #pragma unroll
  for (int mf = 0; mf < 4; ++mf){ acc[mf][0] = (f32x4){0.f,0.f,0.f,0.f}; acc[mf][1] = (f32x4){0.f,0.f,0.f,0.f}; }
  for (int kb = 0; kb < 8; ++kb){
    bf16x8 a[4], b[2];
    #pragma unroll
    for (int mf = 0; mf < 4; ++mf){
      int row = mf*16 + (l & 15);
      int byte = (row << 9) + kb*64 + ((l >> 4) << 4);
      byte ^= (row & 7) << 4;
      a[mf] = *(const bf16x8*)(smem + byte);
    }
    #pragma unroll
    for (int nf = 0; nf < 2; ++nf){
      int nb = wn*2 + nf;
      b[nf] = *(const bf16x8*)(Wr_pk + ((size_t)(nb*8 + kb)*64 + l)*8);
    }
    #pragma unroll
    for (int mf = 0; mf < 4; ++mf)
      #pragma unroll
      for (int nf = 0; nf < 2; ++nf)
        acc[mf][nf] = __builtin_amdgcn_mfma_f32_16x16x32_bf16(a[mf], b[nf], acc[mf][nf], 0, 0, 0);
  }
  __syncthreads();
  // epilogue 1: + cv(rel) -> sRL bf16 [64][128], swizzle (row&12)<<3
  #pragma unroll
  for (int mf = 0; mf < 4; ++mf)
    #pragma unroll
    for (int nf = 0; nf < 2; ++nf){
      int col = wn*32 + nf*16 + (l & 15);
      float cc = cv[128 + col];
      #pragma unroll
      for (int r = 0; r < 4; ++r){
        int row = mf*16 + ((l >> 4) << 2) + r;
        int byte = (row << 8) + (col << 1);
        byte ^= (row & 12) << 3;
        *(unsigned short*)((char*)sRL + byte) = f2bf(acc[mf][nf][r] + cc);
      }
    }
  __syncthreads();
  // compose: wave wn handles its edges [wn*16, +16); direct gathers (TLP hides them)
  #pragma unroll
  for (int j = 0; j < 16; ++j){
    int er = wn*16 + j;
    int e = e0 + er;
    int byteL = (er << 8) + (l << 1);      byteL ^= (er & 12) << 3;        // sRL left
    int byteR = (er << 8) + ((64+l) << 1); byteR ^= (er & 12) << 3;        // sRL right
    int bL = (er << 7) + (l << 1);         bL ^= (er & 12) << 3;           // sLc
    int bR = (er << 7) + (l << 1);         bR ^= (er & 7) << 4;            // sRin
    unsigned short lh16 = 0, rr16 = 0;
    if (e < N_EDGES){
      int s  = __shfl(idxv, j);
      int d2 = __shfl(idxv, 16 + j);
      int b  = __shfl(idxv, 32 + j);
      unsigned qv = qctx_p[b*64 + l];
      float lh = leaky(bf2f(node_l[(size_t)s*64 + l]) + bf2f(*(unsigned short*)((char*)sRL + byteL))
                       + bf2f((unsigned short)(qv & 0xFFFFu)));
      float rr = leaky(bf2f(node_r[(size_t)d2*64 + l]) + bf2f(*(unsigned short*)((char*)sRL + byteR))
                       + bf2f((unsigned short)(qv >> 16)));
      lh16 = f2bf(lh); rr16 = f2bf(rr);
    }
    *(unsigned short*)(sLc + bL) = lh16;
    *(unsigned short*)(sRin + bR) = rr16;
  }
  // no barrier: GEMM2/dot below read only this wave's own rows

  // GEMM2: wave wn computes RH rows [wn*16,+16) x ALL 64 cols (4 col-frags)
  float bcv[4];
  #pragma unroll
  for (int nf = 0; nf < 4; ++nf) bcv[nf] = bc[nf*16 + (l & 15)];
  f32x4 acc2[4];
  #pragma unroll
  for (int nf = 0; nf < 4; ++nf) acc2[nf] = (f32x4){0.f,0.f,0.f,0.f};
  #pragma unroll
  for (int kb = 0; kb < 2; ++kb){
    int row = wn*16 + (l & 15);
    int byte = (row << 7) + kb*64 + ((l >> 4) << 4);
    byte ^= (row & 7) << 4;
    bf16x8 a = *(const bf16x8*)(sRin + byte);
    #pragma unroll
    for (int nf = 0; nf < 4; ++nf){
      bf16x8 bfr = *(const bf16x8*)(Wc_pk + ((size_t)(nf*2 + kb)*64 + l)*8);
      acc2[nf] = __builtin_amdgcn_mfma_f32_16x16x32_bf16(a, bfr, acc2[nf], 0, 0, 0);
    }
  }
  // logit[row] = sum_col (RH+bc)*lh : in-register over nf, shfl over 16-lane group
  int srcj[4];
  float vr[4];
  #pragma unroll
  for (int r = 0; r < 4; ++r){
    int rowl = ((l >> 4) << 2) + r;           // edge index within wave
    srcj[r] = __shfl(idxv, rowl);             // src of that edge (all lanes active)
    int row = wn*16 + rowl;
    float v = 0.f;
    #pragma unroll
    for (int nf = 0; nf < 4; ++nf){
      int col = nf*16 + (l & 15);
      int byte = (row << 7) + (col << 1);
      byte ^= (row & 12) << 3;
      v += (acc2[nf][r] + bcv[nf]) * bf2f(*(unsigned short*)(sLc + byte));
    }
    v += __shfl_xor(v, 1); v += __shfl_xor(v, 2);
    v += __shfl_xor(v, 4); v += __shfl_xor(v, 8);
    vr[r] = v;
  }
  // tail: ex = exp(logit) (|logit| bounded ~8, shift-invariant softmax), denom atomic
  if ((l & 15) == 0){
    #pragma unroll
    for (int r = 0; r < 4; ++r){
      int rowl = ((l >> 4) << 2) + r;
      int e = e0 + wn*16 + rowl;
      if (e < N_EDGES){
        float ex = __expf(vr[r]);
        exbuf[e] = ex;
        atomicAdd(&denom[srcj[r]], ex);
      }
    }
  }
}

// ---------------- final pass: trans + propagate + entity aggregate ----------------
__global__ void k_passC(const float* __restrict__ exbuf, const float* __restrict__ denom,
                        const int* __restrict__ src, const int* __restrict__ dst,
                        const float* __restrict__ node_score, const int* __restrict__ ent,
                        float* __restrict__ out){
  int e = blockIdx.x*256 + threadIdx.x;
  if (e >= N_EDGES) return;
  int s = src[e];
  float tr = exbuf[e] / denom[s];
  atomicAdd(&out[ent[dst[e]]], tr * node_score[s]);
}

// ---------------- host ----------------
extern "C" void kernel_launch(void* const* d_in, const int* in_sizes, int n_in,
                              void* d_out, int out_size, void* d_ws, size_t ws_size,
                              hipStream_t stream){
  const float* mem   = (const float*)d_in[0];
  const float* nsc   = (const float*)d_in[1];
  const float* relE  = (const float*)d_in[2];
  const float* qsrc  = (const float*)d_in[3];
  const float* qrel  = (const float*)d_in[4];
  const int*   eg    = (const int*)d_in[5];
  const int*   src   = (const int*)d_in[6];
  const int*   dst   = (const int*)d_in[7];
  const int*   ent   = (const int*)d_in[8];
  const float* Wp    = (const float*)d_in[9];
  const float* bp    = (const float*)d_in[10];
  const float* Ws    = (const float*)d_in[11];
  const float* bs    = (const float*)d_in[12];
  const float* Wbs   = (const float*)d_in[13];
  const float* bbs   = (const float*)d_in[14];
  const float* Wl    = (const float*)d_in[15];
  const float* bl    = (const float*)d_in[16];
  const float* Wr    = (const float*)d_in[17];
  const float* br    = (const float*)d_in[18];
  const float* Wc    = (const float*)d_in[19];
  const float* bc    = (const float*)d_in[20];
  float* out = (float*)d_out;

  char* w = (char*)d_ws;
  auto alloc = [&](size_t bytes)->void*{
    void* p = (void*)w; w += (bytes + 255) & ~(size_t)255; return p;
  };
  float* Wnlr = (float*)alloc(32768*4);
  float* Wrlr = (float*)alloc(32768*4);
  unsigned short* Wbs_pk = (unsigned short*)alloc(65536*2);
  unsigned short* Wn_pk  = (unsigned short*)alloc(32768*2);
  unsigned short* Wr_pk  = (unsigned short*)alloc(32768*2);
  unsigned short* Wc_pk  = (unsigned short*)alloc(4096*2);
  float* cv  = (float*)alloc(256*4);
  float* qs  = (float*)alloc((size_t)N_Q*SSM*4);
  float* qr  = (float*)alloc((size_t)N_Q*DSM*4);
  unsigned* qctx_p = (unsigned*)alloc((size_t)N_Q*DSM*4);
  unsigned short* node_l = (unsigned short*)alloc((size_t)N_NODES*64*2);
  unsigned short* node_r = (unsigned short*)alloc((size_t)N_NODES*64*2);
  float* exbuf  = (float*)alloc((size_t)N_EDGES*4);
  float* denom = (float*)alloc((size_t)N_NODES*4);

  k_setup1<<<1121, 256, 0, stream>>>(out, denom,
                                     Wp, Wl, Wr, Wnlr, Wrlr, bp, cv,
                                     qsrc, Ws, bs, qrel, qs, qr,
                                     Wbs, Wbs_pk, Wc, Wc_pk);
  k_setup2<<<64, 256, 0, stream>>>(qs, qr, Wl, bl, Wr, br, qctx_p,
                                   Wnlr, Wn_pk, Wrlr, Wr_pk);
  k_node<<<N_NODES/64, 256, 0, stream>>>(mem, Wbs_pk, bbs, Wn_pk, cv, node_l, node_r);
  k_edge<<<(N_EDGES+63)/64, 256, 0, stream>>>(relE, Wr_pk, Wc_pk, cv, bc,
                                              node_l, node_r, qctx_p,
                                              src, dst, eg, exbuf, denom);
  k_passC<<<(N_EDGES+255)/256, 256, 0, stream>>>(exbuf, denom, src, dst, nsc, ent, out);
}